// Round 4
// baseline (3293.989 us; speedup 1.0000x reference)
//
#include <hip/hip_runtime.h>

typedef float f4 __attribute__((ext_vector_type(4)));

#define NE 800000
#define NN 50000
#define LAT 128
#define KE 192
#define FOUT 64

#define XS_E 196   // LDS stride for edge x tile [64][192]
#define XS_N 132   // LDS stride for node x tile [64][128]
#define HS 132     // LDS stride for h tile [64][128]
#define OS 68      // LDS stride for out tile [64][64]
#define OUT_OFF 8448
#define LDS_FLOATS 12800  // 51.2 KB -> 3 blocks/CU

// ---- software-pipeline building blocks (register double-buffer) ----
#define LD_W(WV, WP, NSTRIDE, kb)                                  \
  _Pragma("unroll") for (int kk = 0; kk < 4; kk++) {               \
    WV[kk][0] = *(const f4*)&WP[(kb + kk) * NSTRIDE + j0];         \
    WV[kk][1] = *(const f4*)&WP[(kb + kk) * NSTRIDE + j0 + 4];     \
  }

#define LD_X4(XV, XSTRIDE, kb)                                     \
  _Pragma("unroll") for (int i = 0; i < 4; i++)                    \
    XV[i] = *(const f4*)&lds[(eg * 4 + i) * XSTRIDE + (kb)];

#define LD_X2(XV, XSTRIDE, kb)                                     \
  _Pragma("unroll") for (int i = 0; i < 2; i++)                    \
    XV[i] = *(const f4*)&lds[(eg2 * 2 + i) * XSTRIDE + (kb)];

#define FMA4(ACC, XV, WV)                                          \
  _Pragma("unroll") for (int i = 0; i < 4; i++) {                  \
    _Pragma("unroll") for (int kk = 0; kk < 4; kk++) {             \
      const float xs_ = XV[i][kk];                                 \
      _Pragma("unroll") for (int j = 0; j < 4; j++) {              \
        ACC[i][j] += xs_ * WV[kk][0][j];                           \
        ACC[i][j + 4] += xs_ * WV[kk][1][j];                       \
      }                                                            \
    }                                                              \
  }

#define FMA2(ACC, XV, WV)                                          \
  _Pragma("unroll") for (int i = 0; i < 2; i++) {                  \
    _Pragma("unroll") for (int kk = 0; kk < 4; kk++) {             \
      const float xs_ = XV[i][kk];                                 \
      _Pragma("unroll") for (int j = 0; j < 4; j++) {              \
        ACC[i][j] += xs_ * WV[kk][0][j];                           \
        ACC[i][j + 4] += xs_ * WV[kk][1][j];                       \
      }                                                            \
    }                                                              \
  }

__global__ void zero_kernel(float* __restrict__ p, int n4) {
  int i = blockIdx.x * blockDim.x + threadIdx.x;
  if (i < n4) ((f4*)p)[i] = f4{0.f, 0.f, 0.f, 0.f};
}

__global__ __launch_bounds__(256, 3)
void edge_mlp_kernel(const float* __restrict__ edge_attr,
                     const float* __restrict__ node_attr,
                     const int* __restrict__ eidx,
                     const float* __restrict__ W1,
                     const float* __restrict__ b1,
                     const float* __restrict__ W2,
                     const float* __restrict__ b2,
                     const float* __restrict__ gamma,
                     const float* __restrict__ beta,
                     float* __restrict__ edge_out,
                     float* __restrict__ agg) {
  __shared__ float lds[LDS_FLOATS];
  __shared__ int s_row[64];
  __shared__ int s_col[64];
  const int t = threadIdx.x;
  const long e0 = (long)blockIdx.x * 64;

  if (t < 64) s_row[t] = eidx[e0 + t];
  else if (t < 128) s_col[t - 64] = eidx[NE + e0 + (t - 64)];
  __syncthreads();

  // ---- stage x = [receiver | sender | edge_attr] -> lds[e][0..191] ----
  {
    const int e = t >> 2, q = t & 3;
    const f4* rsrc = (const f4*)(node_attr + (size_t)s_col[e] * 64 + q * 16);
    const f4* ssrc = (const f4*)(node_attr + (size_t)s_row[e] * 64 + q * 16);
    const f4* esrc = (const f4*)(edge_attr + (size_t)(e0 + e) * 64 + q * 16);
    f4* xr = (f4*)&lds[e * XS_E + q * 16];
#pragma unroll
    for (int i = 0; i < 4; i++) xr[i] = rsrc[i];
    f4* xs = (f4*)&lds[e * XS_E + 64 + q * 16];
#pragma unroll
    for (int i = 0; i < 4; i++) xs[i] = ssrc[i];
    f4* xe = (f4*)&lds[e * XS_E + 128 + q * 16];
#pragma unroll
    for (int i = 0; i < 4; i++) xe[i] = esrc[i];
  }
  __syncthreads();

  // ---- layer 1: h = relu(x @ W1 + b1), K=192 -> 128, pipelined ----
  const int jg = t & 15, eg = t >> 4;
  const int j0 = jg * 8;
  float acc[4][8];
#pragma unroll
  for (int i = 0; i < 4; i++)
#pragma unroll
    for (int j = 0; j < 8; j++) acc[i][j] = 0.f;

  {
    f4 xa[4], xb[4], wa[4][2], wb[4][2];
    LD_W(wa, W1, LAT, 0)
    LD_X4(xa, XS_E, 0)
    for (int k = 0; k < KE; k += 8) {
      const int k4 = k + 4;
      LD_W(wb, W1, LAT, k4)
      LD_X4(xb, XS_E, k4)
      FMA4(acc, xa, wa)
      const int k8 = (k + 8 < KE) ? k + 8 : 0;  // clamped dummy prefetch on last iter
      LD_W(wa, W1, LAT, k8)
      LD_X4(xa, XS_E, k8)
      FMA4(acc, xb, wb)
    }
  }
  __syncthreads();  // all x reads done; h overlays x region

  {
    const f4 bb0 = *(const f4*)&b1[j0];
    const f4 bb1 = *(const f4*)&b1[j0 + 4];
#pragma unroll
    for (int i = 0; i < 4; i++) {
      f4 h0, h1;
#pragma unroll
      for (int j = 0; j < 4; j++) {
        h0[j] = fmaxf(acc[i][j] + bb0[j], 0.f);
        h1[j] = fmaxf(acc[i][j + 4] + bb1[j], 0.f);
      }
      *(f4*)&lds[(eg * 4 + i) * HS + j0] = h0;
      *(f4*)&lds[(eg * 4 + i) * HS + j0 + 4] = h1;
    }
  }
  __syncthreads();

  // ---- layer 2: o = relu(h @ W2 + b2), K=128 -> 64, pipelined ----
  const int og = t & 7, eg2 = t >> 3;
  const int o0 = og * 8;
  float acc2[2][8];
#pragma unroll
  for (int i = 0; i < 2; i++)
#pragma unroll
    for (int j = 0; j < 8; j++) acc2[i][j] = 0.f;

  {
    const int j0 = o0;  // LD_W uses j0
    f4 xa[2], xb[2], wa[4][2], wb[4][2];
    LD_W(wa, W2, FOUT, 0)
    LD_X2(xa, HS, 0)
    for (int k = 0; k < LAT; k += 8) {
      const int k4 = k + 4;
      LD_W(wb, W2, FOUT, k4)
      LD_X2(xb, HS, k4)
      FMA2(acc2, xa, wa)
      const int k8 = (k + 8 < LAT) ? k + 8 : 0;
      LD_W(wa, W2, FOUT, k8)
      LD_X2(xa, HS, k8)
      FMA2(acc2, xb, wb)
    }
  }
  {
    const f4 bb0 = *(const f4*)&b2[o0];
    const f4 bb1 = *(const f4*)&b2[o0 + 4];
#pragma unroll
    for (int i = 0; i < 2; i++) {
      f4 v0, v1;
#pragma unroll
      for (int j = 0; j < 4; j++) {
        v0[j] = fmaxf(acc2[i][j] + bb0[j], 0.f);
        v1[j] = fmaxf(acc2[i][j + 4] + bb1[j], 0.f);
      }
      *(f4*)&lds[OUT_OFF + (eg2 * 2 + i) * OS + o0] = v0;
      *(f4*)&lds[OUT_OFF + (eg2 * 2 + i) * OS + o0 + 4] = v1;
    }
  }
  __syncthreads();

  // ---- LayerNorm + store + scatter-add into agg ----
  {
    const int e = t >> 2, p = t & 3;
    f4 v[4];
#pragma unroll
    for (int i = 0; i < 4; i++)
      v[i] = *(const f4*)&lds[OUT_OFF + e * OS + p * 16 + i * 4];
    float s = 0.f, s2 = 0.f;
#pragma unroll
    for (int i = 0; i < 4; i++)
#pragma unroll
      for (int j = 0; j < 4; j++) {
        s += v[i][j];
        s2 += v[i][j] * v[i][j];
      }
    s += __shfl_xor(s, 1);
    s += __shfl_xor(s, 2);
    s2 += __shfl_xor(s2, 1);
    s2 += __shfl_xor(s2, 2);
    const float mu = s * (1.f / 64.f);
    const float var = s2 * (1.f / 64.f) - mu * mu;
    const float rstd = rsqrtf(var + 1e-5f);
    float* op = edge_out + (size_t)(e0 + e) * 64 + p * 16;
    float* ap = agg + (size_t)s_col[e] * 64 + p * 16;
#pragma unroll
    for (int i = 0; i < 4; i++) {
      const f4 g = *(const f4*)&gamma[p * 16 + i * 4];
      const f4 bt = *(const f4*)&beta[p * 16 + i * 4];
      f4 o;
#pragma unroll
      for (int j = 0; j < 4; j++) o[j] = (v[i][j] - mu) * rstd * g[j] + bt[j];
      *(f4*)&op[i * 4] = o;
#pragma unroll
      for (int j = 0; j < 4; j++) atomicAdd(&ap[i * 4 + j], o[j]);
    }
  }
}

__global__ __launch_bounds__(256, 3)
void node_mlp_kernel(const float* __restrict__ node_attr,
                     const float* __restrict__ agg,
                     const float* __restrict__ W1,
                     const float* __restrict__ b1,
                     const float* __restrict__ W2,
                     const float* __restrict__ b2,
                     const float* __restrict__ gamma,
                     const float* __restrict__ beta,
                     float* __restrict__ node_out) {
  __shared__ float lds[LDS_FLOATS];
  const int t = threadIdx.x;
  const long n0 = (long)blockIdx.x * 64;

  // ---- stage x = [node_attr | agg] -> lds[r][0..127] ----
  {
    const int r = t >> 2, q = t & 3;
    long n = n0 + r;
    if (n >= NN) n = NN - 1;  // clamp loads; stores are guarded
    const f4* src = (q < 2) ? (const f4*)(node_attr + (size_t)n * 64 + q * 32)
                            : (const f4*)(agg + (size_t)n * 64 + (q - 2) * 32);
    f4* xd = (f4*)&lds[r * XS_N + q * 32];
#pragma unroll
    for (int i = 0; i < 8; i++) xd[i] = src[i];
  }
  __syncthreads();

  // ---- layer 1: K=128 -> 128, pipelined ----
  const int jg = t & 15, eg = t >> 4;
  const int j0 = jg * 8;
  float acc[4][8];
#pragma unroll
  for (int i = 0; i < 4; i++)
#pragma unroll
    for (int j = 0; j < 8; j++) acc[i][j] = 0.f;

  {
    f4 xa[4], xb[4], wa[4][2], wb[4][2];
    LD_W(wa, W1, LAT, 0)
    LD_X4(xa, XS_N, 0)
    for (int k = 0; k < LAT; k += 8) {
      const int k4 = k + 4;
      LD_W(wb, W1, LAT, k4)
      LD_X4(xb, XS_N, k4)
      FMA4(acc, xa, wa)
      const int k8 = (k + 8 < LAT) ? k + 8 : 0;
      LD_W(wa, W1, LAT, k8)
      LD_X4(xa, XS_N, k8)
      FMA4(acc, xb, wb)
    }
  }
  __syncthreads();

  {
    const f4 bb0 = *(const f4*)&b1[j0];
    const f4 bb1 = *(const f4*)&b1[j0 + 4];
#pragma unroll
    for (int i = 0; i < 4; i++) {
      f4 h0, h1;
#pragma unroll
      for (int j = 0; j < 4; j++) {
        h0[j] = fmaxf(acc[i][j] + bb0[j], 0.f);
        h1[j] = fmaxf(acc[i][j + 4] + bb1[j], 0.f);
      }
      *(f4*)&lds[(eg * 4 + i) * HS + j0] = h0;
      *(f4*)&lds[(eg * 4 + i) * HS + j0 + 4] = h1;
    }
  }
  __syncthreads();

  // ---- layer 2: K=128 -> 64, pipelined ----
  const int og = t & 7, eg2 = t >> 3;
  const int o0 = og * 8;
  float acc2[2][8];
#pragma unroll
  for (int i = 0; i < 2; i++)
#pragma unroll
    for (int j = 0; j < 8; j++) acc2[i][j] = 0.f;

  {
    const int j0 = o0;
    f4 xa[2], xb[2], wa[4][2], wb[4][2];
    LD_W(wa, W2, FOUT, 0)
    LD_X2(xa, HS, 0)
    for (int k = 0; k < LAT; k += 8) {
      const int k4 = k + 4;
      LD_W(wb, W2, FOUT, k4)
      LD_X2(xb, HS, k4)
      FMA2(acc2, xa, wa)
      const int k8 = (k + 8 < LAT) ? k + 8 : 0;
      LD_W(wa, W2, FOUT, k8)
      LD_X2(xa, HS, k8)
      FMA2(acc2, xb, wb)
    }
  }
  {
    const f4 bb0 = *(const f4*)&b2[o0];
    const f4 bb1 = *(const f4*)&b2[o0 + 4];
#pragma unroll
    for (int i = 0; i < 2; i++) {
      f4 v0, v1;
#pragma unroll
      for (int j = 0; j < 4; j++) {
        v0[j] = fmaxf(acc2[i][j] + bb0[j], 0.f);
        v1[j] = fmaxf(acc2[i][j + 4] + bb1[j], 0.f);
      }
      *(f4*)&lds[OUT_OFF + (eg2 * 2 + i) * OS + o0] = v0;
      *(f4*)&lds[OUT_OFF + (eg2 * 2 + i) * OS + o0 + 4] = v1;
    }
  }
  __syncthreads();

  // ---- LayerNorm + store ----
  {
    const int e = t >> 2, p = t & 3;
    f4 v[4];
#pragma unroll
    for (int i = 0; i < 4; i++)
      v[i] = *(const f4*)&lds[OUT_OFF + e * OS + p * 16 + i * 4];
    float s = 0.f, s2 = 0.f;
#pragma unroll
    for (int i = 0; i < 4; i++)
#pragma unroll
      for (int j = 0; j < 4; j++) {
        s += v[i][j];
        s2 += v[i][j] * v[i][j];
      }
    s += __shfl_xor(s, 1);
    s += __shfl_xor(s, 2);
    s2 += __shfl_xor(s2, 1);
    s2 += __shfl_xor(s2, 2);
    const float mu = s * (1.f / 64.f);
    const float var = s2 * (1.f / 64.f) - mu * mu;
    const float rstd = rsqrtf(var + 1e-5f);
    if (n0 + e < NN) {
      float* op = node_out + (size_t)(n0 + e) * 64 + p * 16;
#pragma unroll
      for (int i = 0; i < 4; i++) {
        const f4 g = *(const f4*)&gamma[p * 16 + i * 4];
        const f4 bt = *(const f4*)&beta[p * 16 + i * 4];
        f4 o;
#pragma unroll
        for (int j = 0; j < 4; j++) o[j] = (v[i][j] - mu) * rstd * g[j] + bt[j];
        *(f4*)&op[i * 4] = o;
      }
    }
  }
}

extern "C" void kernel_launch(void* const* d_in, const int* in_sizes, int n_in,
                              void* d_out, int out_size, void* d_ws, size_t ws_size,
                              hipStream_t stream) {
  const float* edge_attr = (const float*)d_in[0];
  const float* node_attr = (const float*)d_in[1];
  const int* eidx = (const int*)d_in[2];
  // d_in[3] = batch (unused)
  const float* eW1 = (const float*)d_in[4];
  const float* eb1 = (const float*)d_in[5];
  const float* eW2 = (const float*)d_in[6];
  const float* eb2 = (const float*)d_in[7];
  const float* eg = (const float*)d_in[8];
  const float* ebt = (const float*)d_in[9];
  const float* nW1 = (const float*)d_in[10];
  const float* nb1 = (const float*)d_in[11];
  const float* nW2 = (const float*)d_in[12];
  const float* nb2 = (const float*)d_in[13];
  const float* ng = (const float*)d_in[14];
  const float* nbt = (const float*)d_in[15];

  float* out_edge = (float*)d_out;
  float* out_node = out_edge + (size_t)NE * 64;
  float* agg = (float*)d_ws;  // [NN][64] accumulator

  const int n4 = NN * 64 / 4;
  zero_kernel<<<(n4 + 255) / 256, 256, 0, stream>>>(agg, n4);
  edge_mlp_kernel<<<NE / 64, 256, 0, stream>>>(edge_attr, node_attr, eidx,
                                               eW1, eb1, eW2, eb2, eg, ebt,
                                               out_edge, agg);
  node_mlp_kernel<<<(NN + 63) / 64, 256, 0, stream>>>(node_attr, agg,
                                                      nW1, nb1, nW2, nb2, ng, nbt,
                                                      out_node);
}

// Round 5
// 2113.470 us; speedup vs baseline: 1.5586x; 1.5586x over previous
//
#include <hip/hip_runtime.h>

typedef float f4 __attribute__((ext_vector_type(4)));

#define NE 800000
#define NN 50000
#define LAT 128
#define KE 192
#define FOUT 64

// ---- edge kernel LDS layout (float indices) ----
#define E_XS   196                    // x/h row stride (64 rows)
#define E_XSZ  (64 * E_XS)            // 12544
#define E_WOFF E_XSZ                  // W region (W1: 192x128, later W2: 128x64)
#define E_W1SZ (KE * LAT)             // 24576
#define E_OOFF (E_WOFF + LAT * FOUT)  // out tile at 20736 (inside W region tail)
#define E_OS   68
#define E_LDS  (E_XSZ + E_W1SZ)       // 37120 floats = 148480 B

// ---- node kernel LDS layout ----
#define N_XS   132
#define N_XSZ  (64 * N_XS)            // 8448
#define N_WOFF N_XSZ
#define N_W1SZ (LAT * LAT)            // 16384
#define N_OOFF (N_WOFF + LAT * FOUT)  // 16640
#define N_LDS  (N_XSZ + N_W1SZ)       // 24832 floats = 99328 B

__global__ void zero_kernel(float* __restrict__ p, int n4) {
  int i = blockIdx.x * blockDim.x + threadIdx.x;
  if (i < n4) ((f4*)p)[i] = f4{0.f, 0.f, 0.f, 0.f};
}

__global__ __launch_bounds__(512, 2)
void edge_mlp_kernel(const float* __restrict__ edge_attr,
                     const float* __restrict__ node_attr,
                     const int* __restrict__ eidx,
                     const float* __restrict__ W1,
                     const float* __restrict__ b1,
                     const float* __restrict__ W2,
                     const float* __restrict__ b2,
                     const float* __restrict__ gamma,
                     const float* __restrict__ beta,
                     float* __restrict__ edge_out,
                     float* __restrict__ agg) {
  __shared__ float lds[E_LDS];
  __shared__ int s_row[64];
  __shared__ int s_col[64];
  const int t = threadIdx.x;
  const long e0 = (long)blockIdx.x * 64;

  if (t < 64) s_row[t] = eidx[e0 + t];
  else if (t < 128) s_col[t - 64] = eidx[NE + e0 + (t - 64)];
  __syncthreads();

  // ---- stage W1 (coalesced, once per block) + x gather ----
  {
#pragma unroll
    for (int i = 0; i < 12; i++)
      ((f4*)&lds[E_WOFF])[t + 512 * i] = ((const f4*)W1)[t + 512 * i];

    const int r = t >> 3, q = t & 7;  // 8 threads per row
    const f4* rsrc = (const f4*)(node_attr + (size_t)s_col[r] * 64) + q * 2;
    const f4* ssrc = (const f4*)(node_attr + (size_t)s_row[r] * 64) + q * 2;
    const f4* esrc = (const f4*)(edge_attr + (size_t)(e0 + r) * 64) + q * 2;
#pragma unroll
    for (int i = 0; i < 2; i++) *(f4*)&lds[r * E_XS + q * 8 + 4 * i] = rsrc[i];
#pragma unroll
    for (int i = 0; i < 2; i++) *(f4*)&lds[r * E_XS + 64 + q * 8 + 4 * i] = ssrc[i];
#pragma unroll
    for (int i = 0; i < 2; i++) *(f4*)&lds[r * E_XS + 128 + q * 8 + 4 * i] = esrc[i];
  }
  __syncthreads();

  // ---- layer 1: h = relu(x @ W1 + b1), K=192 -> 128, weights from LDS ----
  const int jg = t & 15, eg = t >> 4;  // eg 0..31 -> rows 2eg..2eg+1
  const int j0 = jg * 8;
  float acc[2][8];
#pragma unroll
  for (int i = 0; i < 2; i++)
#pragma unroll
    for (int j = 0; j < 8; j++) acc[i][j] = 0.f;

  for (int k = 0; k < KE; k += 4) {
    f4 xv[2];
#pragma unroll
    for (int i = 0; i < 2; i++) xv[i] = *(const f4*)&lds[(eg * 2 + i) * E_XS + k];
    f4 wv[4][2];
#pragma unroll
    for (int kk = 0; kk < 4; kk++) {
      wv[kk][0] = *(const f4*)&lds[E_WOFF + (k + kk) * LAT + j0];
      wv[kk][1] = *(const f4*)&lds[E_WOFF + (k + kk) * LAT + j0 + 4];
    }
#pragma unroll
    for (int i = 0; i < 2; i++) {
#pragma unroll
      for (int kk = 0; kk < 4; kk++) {
        const float xs_ = xv[i][kk];
#pragma unroll
        for (int j = 0; j < 4; j++) {
          acc[i][j] += xs_ * wv[kk][0][j];
          acc[i][j + 4] += xs_ * wv[kk][1][j];
        }
      }
    }
  }
  __syncthreads();  // x reads + W1 reads done (h overlays x; W2 overlays W1)

  {
    const f4 bb0 = *(const f4*)&b1[j0];
    const f4 bb1 = *(const f4*)&b1[j0 + 4];
#pragma unroll
    for (int i = 0; i < 2; i++) {
      f4 h0, h1;
#pragma unroll
      for (int j = 0; j < 4; j++) {
        h0[j] = fmaxf(acc[i][j] + bb0[j], 0.f);
        h1[j] = fmaxf(acc[i][j + 4] + bb1[j], 0.f);
      }
      *(f4*)&lds[(eg * 2 + i) * E_XS + j0] = h0;
      *(f4*)&lds[(eg * 2 + i) * E_XS + j0 + 4] = h1;
    }
    // stage W2 into the W region (W1 is dead)
#pragma unroll
    for (int i = 0; i < 4; i++)
      ((f4*)&lds[E_WOFF])[t + 512 * i] = ((const f4*)W2)[t + 512 * i];
  }
  __syncthreads();

  // ---- layer 2: o = relu(h @ W2 + b2), K=128 -> 64 ----
  const int og = t & 7, e2 = t >> 3;  // e2 0..63 (one row per thread-group of 8)
  const int o0 = og * 8;
  float acc2[8];
#pragma unroll
  for (int j = 0; j < 8; j++) acc2[j] = 0.f;

  for (int k = 0; k < LAT; k += 4) {
    const f4 xv = *(const f4*)&lds[e2 * E_XS + k];
    f4 wv[4][2];
#pragma unroll
    for (int kk = 0; kk < 4; kk++) {
      wv[kk][0] = *(const f4*)&lds[E_WOFF + (k + kk) * FOUT + o0];
      wv[kk][1] = *(const f4*)&lds[E_WOFF + (k + kk) * FOUT + o0 + 4];
    }
#pragma unroll
    for (int kk = 0; kk < 4; kk++) {
      const float xs_ = xv[kk];
#pragma unroll
      for (int j = 0; j < 4; j++) {
        acc2[j] += xs_ * wv[kk][0][j];
        acc2[j + 4] += xs_ * wv[kk][1][j];
      }
    }
  }
  {
    const f4 bb0 = *(const f4*)&b2[o0];
    const f4 bb1 = *(const f4*)&b2[o0 + 4];
    f4 v0, v1;
#pragma unroll
    for (int j = 0; j < 4; j++) {
      v0[j] = fmaxf(acc2[j] + bb0[j], 0.f);
      v1[j] = fmaxf(acc2[j + 4] + bb1[j], 0.f);
    }
    *(f4*)&lds[E_OOFF + e2 * E_OS + o0] = v0;
    *(f4*)&lds[E_OOFF + e2 * E_OS + o0 + 4] = v1;
  }
  __syncthreads();

  // ---- LayerNorm + store + scatter-add ----
  {
    const int e = t >> 3, p = t & 7;  // 8 lanes per row, 8 cols each
    f4 v0 = *(const f4*)&lds[E_OOFF + e * E_OS + p * 8];
    f4 v1 = *(const f4*)&lds[E_OOFF + e * E_OS + p * 8 + 4];
    float s = 0.f, s2 = 0.f;
#pragma unroll
    for (int j = 0; j < 4; j++) {
      s += v0[j] + v1[j];
      s2 += v0[j] * v0[j] + v1[j] * v1[j];
    }
    s += __shfl_xor(s, 1);
    s += __shfl_xor(s, 2);
    s += __shfl_xor(s, 4);
    s2 += __shfl_xor(s2, 1);
    s2 += __shfl_xor(s2, 2);
    s2 += __shfl_xor(s2, 4);
    const float mu = s * (1.f / 64.f);
    const float var = s2 * (1.f / 64.f) - mu * mu;
    const float rstd = rsqrtf(var + 1e-5f);
    const f4 g0 = *(const f4*)&gamma[p * 8];
    const f4 g1 = *(const f4*)&gamma[p * 8 + 4];
    const f4 bt0 = *(const f4*)&beta[p * 8];
    const f4 bt1 = *(const f4*)&beta[p * 8 + 4];
    f4 o0v, o1v;
#pragma unroll
    for (int j = 0; j < 4; j++) {
      o0v[j] = (v0[j] - mu) * rstd * g0[j] + bt0[j];
      o1v[j] = (v1[j] - mu) * rstd * g1[j] + bt1[j];
    }
    float* op = edge_out + (size_t)(e0 + e) * 64 + p * 8;
    *(f4*)&op[0] = o0v;
    *(f4*)&op[4] = o1v;
    float* ap = agg + (size_t)s_col[e] * 64 + p * 8;
#pragma unroll
    for (int j = 0; j < 4; j++) {
      atomicAdd(&ap[j], o0v[j]);
      atomicAdd(&ap[j + 4], o1v[j]);
    }
  }
}

__global__ __launch_bounds__(512, 2)
void node_mlp_kernel(const float* __restrict__ node_attr,
                     const float* __restrict__ agg,
                     const float* __restrict__ W1,
                     const float* __restrict__ b1,
                     const float* __restrict__ W2,
                     const float* __restrict__ b2,
                     const float* __restrict__ gamma,
                     const float* __restrict__ beta,
                     float* __restrict__ node_out) {
  __shared__ float lds[N_LDS];
  const int t = threadIdx.x;
  const long n0 = (long)blockIdx.x * 64;

  // ---- stage W1 + x = [node_attr | agg] ----
  {
#pragma unroll
    for (int i = 0; i < 8; i++)
      ((f4*)&lds[N_WOFF])[t + 512 * i] = ((const f4*)W1)[t + 512 * i];

    const int r = t >> 3, q = t & 7;
    long n = n0 + r;
    if (n >= NN) n = NN - 1;  // clamp loads; stores guarded
    if (q < 4) {
      const f4* src = (const f4*)(node_attr + (size_t)n * 64) + q * 4;
#pragma unroll
      for (int i = 0; i < 4; i++) *(f4*)&lds[r * N_XS + q * 16 + 4 * i] = src[i];
    } else {
      const f4* src = (const f4*)(agg + (size_t)n * 64) + (q - 4) * 4;
#pragma unroll
      for (int i = 0; i < 4; i++)
        *(f4*)&lds[r * N_XS + 64 + (q - 4) * 16 + 4 * i] = src[i];
    }
  }
  __syncthreads();

  // ---- layer 1: K=128 -> 128 ----
  const int jg = t & 15, eg = t >> 4;
  const int j0 = jg * 8;
  float acc[2][8];
#pragma unroll
  for (int i = 0; i < 2; i++)
#pragma unroll
    for (int j = 0; j < 8; j++) acc[i][j] = 0.f;

  for (int k = 0; k < LAT; k += 4) {
    f4 xv[2];
#pragma unroll
    for (int i = 0; i < 2; i++) xv[i] = *(const f4*)&lds[(eg * 2 + i) * N_XS + k];
    f4 wv[4][2];
#pragma unroll
    for (int kk = 0; kk < 4; kk++) {
      wv[kk][0] = *(const f4*)&lds[N_WOFF + (k + kk) * LAT + j0];
      wv[kk][1] = *(const f4*)&lds[N_WOFF + (k + kk) * LAT + j0 + 4];
    }
#pragma unroll
    for (int i = 0; i < 2; i++) {
#pragma unroll
      for (int kk = 0; kk < 4; kk++) {
        const float xs_ = xv[i][kk];
#pragma unroll
        for (int j = 0; j < 4; j++) {
          acc[i][j] += xs_ * wv[kk][0][j];
          acc[i][j + 4] += xs_ * wv[kk][1][j];
        }
      }
    }
  }
  __syncthreads();

  {
    const f4 bb0 = *(const f4*)&b1[j0];
    const f4 bb1 = *(const f4*)&b1[j0 + 4];
#pragma unroll
    for (int i = 0; i < 2; i++) {
      f4 h0, h1;
#pragma unroll
      for (int j = 0; j < 4; j++) {
        h0[j] = fmaxf(acc[i][j] + bb0[j], 0.f);
        h1[j] = fmaxf(acc[i][j + 4] + bb1[j], 0.f);
      }
      *(f4*)&lds[(eg * 2 + i) * N_XS + j0] = h0;
      *(f4*)&lds[(eg * 2 + i) * N_XS + j0 + 4] = h1;
    }
#pragma unroll
    for (int i = 0; i < 4; i++)
      ((f4*)&lds[N_WOFF])[t + 512 * i] = ((const f4*)W2)[t + 512 * i];
  }
  __syncthreads();

  // ---- layer 2: K=128 -> 64 ----
  const int og = t & 7, e2 = t >> 3;
  const int o0 = og * 8;
  float acc2[8];
#pragma unroll
  for (int j = 0; j < 8; j++) acc2[j] = 0.f;

  for (int k = 0; k < LAT; k += 4) {
    const f4 xv = *(const f4*)&lds[e2 * N_XS + k];
    f4 wv[4][2];
#pragma unroll
    for (int kk = 0; kk < 4; kk++) {
      wv[kk][0] = *(const f4*)&lds[N_WOFF + (k + kk) * FOUT + o0];
      wv[kk][1] = *(const f4*)&lds[N_WOFF + (k + kk) * FOUT + o0 + 4];
    }
#pragma unroll
    for (int kk = 0; kk < 4; kk++) {
      const float xs_ = xv[kk];
#pragma unroll
      for (int j = 0; j < 4; j++) {
        acc2[j] += xs_ * wv[kk][0][j];
        acc2[j + 4] += xs_ * wv[kk][1][j];
      }
    }
  }
  {
    const f4 bb0 = *(const f4*)&b2[o0];
    const f4 bb1 = *(const f4*)&b2[o0 + 4];
    f4 v0, v1;
#pragma unroll
    for (int j = 0; j < 4; j++) {
      v0[j] = fmaxf(acc2[j] + bb0[j], 0.f);
      v1[j] = fmaxf(acc2[j + 4] + bb1[j], 0.f);
    }
    *(f4*)&lds[N_OOFF + e2 * E_OS + o0] = v0;
    *(f4*)&lds[N_OOFF + e2 * E_OS + o0 + 4] = v1;
  }
  __syncthreads();

  // ---- LayerNorm + store ----
  {
    const int e = t >> 3, p = t & 7;
    f4 v0 = *(const f4*)&lds[N_OOFF + e * E_OS + p * 8];
    f4 v1 = *(const f4*)&lds[N_OOFF + e * E_OS + p * 8 + 4];
    float s = 0.f, s2 = 0.f;
#pragma unroll
    for (int j = 0; j < 4; j++) {
      s += v0[j] + v1[j];
      s2 += v0[j] * v0[j] + v1[j] * v1[j];
    }
    s += __shfl_xor(s, 1);
    s += __shfl_xor(s, 2);
    s += __shfl_xor(s, 4);
    s2 += __shfl_xor(s2, 1);
    s2 += __shfl_xor(s2, 2);
    s2 += __shfl_xor(s2, 4);
    const float mu = s * (1.f / 64.f);
    const float var = s2 * (1.f / 64.f) - mu * mu;
    const float rstd = rsqrtf(var + 1e-5f);
    if (n0 + e < NN) {
      const f4 g0 = *(const f4*)&gamma[p * 8];
      const f4 g1 = *(const f4*)&gamma[p * 8 + 4];
      const f4 bt0 = *(const f4*)&beta[p * 8];
      const f4 bt1 = *(const f4*)&beta[p * 8 + 4];
      f4 o0v, o1v;
#pragma unroll
      for (int j = 0; j < 4; j++) {
        o0v[j] = (v0[j] - mu) * rstd * g0[j] + bt0[j];
        o1v[j] = (v1[j] - mu) * rstd * g1[j] + bt1[j];
      }
      float* op = node_out + (size_t)(n0 + e) * 64 + p * 8;
      *(f4*)&op[0] = o0v;
      *(f4*)&op[4] = o1v;
    }
  }
}

extern "C" void kernel_launch(void* const* d_in, const int* in_sizes, int n_in,
                              void* d_out, int out_size, void* d_ws, size_t ws_size,
                              hipStream_t stream) {
  const float* edge_attr = (const float*)d_in[0];
  const float* node_attr = (const float*)d_in[1];
  const int* eidx = (const int*)d_in[2];
  // d_in[3] = batch (unused)
  const float* eW1 = (const float*)d_in[4];
  const float* eb1 = (const float*)d_in[5];
  const float* eW2 = (const float*)d_in[6];
  const float* eb2 = (const float*)d_in[7];
  const float* eg = (const float*)d_in[8];
  const float* ebt = (const float*)d_in[9];
  const float* nW1 = (const float*)d_in[10];
  const float* nb1 = (const float*)d_in[11];
  const float* nW2 = (const float*)d_in[12];
  const float* nb2 = (const float*)d_in[13];
  const float* ng = (const float*)d_in[14];
  const float* nbt = (const float*)d_in[15];

  float* out_edge = (float*)d_out;
  float* out_node = out_edge + (size_t)NE * 64;
  float* agg = (float*)d_ws;  // [NN][64] accumulator

  const int n4 = NN * 64 / 4;
  zero_kernel<<<(n4 + 255) / 256, 256, 0, stream>>>(agg, n4);
  edge_mlp_kernel<<<NE / 64, 512, 0, stream>>>(edge_attr, node_attr, eidx,
                                               eW1, eb1, eW2, eb2, eg, ebt,
                                               out_edge, agg);
  node_mlp_kernel<<<(NN + 63) / 64, 512, 0, stream>>>(node_attr, agg,
                                                      nW1, nb1, nW2, nb2, ng, nbt,
                                                      out_node);
}

// Round 7
// 1629.974 us; speedup vs baseline: 2.0209x; 1.2966x over previous
//
#include <hip/hip_runtime.h>

typedef float f4 __attribute__((ext_vector_type(4)));
typedef __bf16 bf16x8 __attribute__((ext_vector_type(8)));
typedef unsigned short u16;
typedef u16 u16x4 __attribute__((ext_vector_type(4)));
typedef u16 u16x8 __attribute__((ext_vector_type(8)));

#define NE 800000
#define NN 50000

static __device__ __forceinline__ f4 MF(u16x8 a, u16x8 b, f4 c) {
  return __builtin_amdgcn_mfma_f32_16x16x32_bf16(
      __builtin_bit_cast(bf16x8, a), __builtin_bit_cast(bf16x8, b), c, 0, 0, 0);
}

static __device__ __forceinline__ u16 f2bf(float x) {
  unsigned u = __builtin_bit_cast(unsigned, x);
  return (u16)((u + 0x7FFFu + ((u >> 16) & 1u)) >> 16);
}
static __device__ __forceinline__ float bf2f(u16 h) {
  return __builtin_bit_cast(float, ((unsigned)h) << 16);
}

__global__ void zero_kernel(float* __restrict__ p, int n4) {
  int i = blockIdx.x * blockDim.x + threadIdx.x;
  if (i < n4) ((f4*)p)[i] = f4{0.f, 0.f, 0.f, 0.f};
}

// ---- edge kernel LDS (u16 units) ----
// x: 32 rows, 192 cols, stride 200; hi [0,6400), lo [6400,12800)
// h: 32 rows, 128 cols, stride 136; hi [0,4352), lo [6400,10752)  (overlays x)
// ob: fp32 32x64 at u16 ofs 12800 (4096 u16) -> total 16896 u16 = 33792 B
#define E_XS 200
#define E_HS 136
#define E_LO 6400
#define E_OB 12800

__global__ __launch_bounds__(512, 2)
void edge_mlp_kernel(const float* __restrict__ edge_attr,
                     const float* __restrict__ node_attr,
                     const int* __restrict__ eidx,
                     const float* __restrict__ W1, const float* __restrict__ b1,
                     const float* __restrict__ W2, const float* __restrict__ b2,
                     const float* __restrict__ gamma, const float* __restrict__ beta,
                     float* __restrict__ edge_out, float* __restrict__ agg,
                     int ntiles) {
  __shared__ __align__(16) u16 sm[16896];
  const int t = threadIdx.x;
  const int wid = t >> 6, lane = t & 63, g = lane >> 4, l15 = lane & 15;

  // ---- B fragments (weights, bf16 hi/lo) in registers for whole kernel ----
  u16x8 b1h[6], b1l[6], b2h[4], b2l[4];
  {
    const int c1 = wid * 16 + l15;  // L1: wave wid owns cols [16*wid, 16*wid+16)
#pragma unroll
    for (int s = 0; s < 6; s++) {
      u16x8 th, tl;
#pragma unroll
      for (int i = 0; i < 8; i++) {
        float w = W1[(s * 32 + g * 8 + i) * 128 + c1];
        u16 hi = f2bf(w);
        th[i] = hi; tl[i] = f2bf(w - bf2f(hi));
      }
      b1h[s] = th; b1l[s] = tl;
    }
    const int c2 = (wid & 3) * 16 + l15;  // L2: tile (wid>>2, wid&3)
#pragma unroll
    for (int s = 0; s < 4; s++) {
      u16x8 th, tl;
#pragma unroll
      for (int i = 0; i < 8; i++) {
        float w = W2[(s * 32 + g * 8 + i) * 64 + c2];
        u16 hi = f2bf(w);
        th[i] = hi; tl[i] = f2bf(w - bf2f(hi));
      }
      b2h[s] = th; b2l[s] = tl;
    }
  }
  const float bias1 = b1[wid * 16 + l15];
  const float bias2 = b2[(wid & 3) * 16 + l15];
  f4 ga0 = {}, ga1 = {}, be0 = {}, be1 = {};
  if (t < 256) {
    const int p = t & 7;
    ga0 = *(const f4*)&gamma[p * 8]; ga1 = *(const f4*)&gamma[p * 8 + 4];
    be0 = *(const f4*)&beta[p * 8];  be1 = *(const f4*)&beta[p * 8 + 4];
  }

  for (int tile = blockIdx.x; tile < ntiles; tile += gridDim.x) {
    const long ebase = (long)tile * 32;
    __syncthreads();  // protect LDS reuse across iterations

    // ---- gather x = [recv | send | edge] -> bf16 hi/lo planes ----
#pragma unroll
    for (int i = 0; i < 3; i++) {
      const int f = t + 512 * i;
      const int r = f / 48, q = f - r * 48;
      const long e = ebase + r;
      const float* src;
      if (q < 16)      src = node_attr + (size_t)eidx[NE + e] * 64 + q * 4;
      else if (q < 32) src = node_attr + (size_t)eidx[e] * 64 + (q - 16) * 4;
      else             src = edge_attr + (size_t)e * 64 + (q - 32) * 4;
      const f4 v = *(const f4*)src;
      u16x4 h, l;
#pragma unroll
      for (int j = 0; j < 4; j++) {
        u16 hi = f2bf(v[j]); h[j] = hi; l[j] = f2bf(v[j] - bf2f(hi));
      }
      const int idx = r * E_XS + 4 * q;
      *(u16x4*)&sm[idx] = h;
      *(u16x4*)&sm[E_LO + idx] = l;
    }
    __syncthreads();

    // ---- layer 1: 32x128 = x(32x192) @ W1, split-bf16 MFMA ----
    f4 a00 = {0.f, 0.f, 0.f, 0.f}, a01 = {0.f, 0.f, 0.f, 0.f};
#pragma unroll
    for (int s = 0; s < 6; s++) {
      const int i0 = l15 * E_XS + s * 32 + g * 8;
      const u16x8 ah0 = *(const u16x8*)&sm[i0];
      const u16x8 al0 = *(const u16x8*)&sm[E_LO + i0];
      const int i1 = i0 + 16 * E_XS;
      const u16x8 ah1 = *(const u16x8*)&sm[i1];
      const u16x8 al1 = *(const u16x8*)&sm[E_LO + i1];
      a00 = MF(al0, b1h[s], a00);
      a00 = MF(ah0, b1l[s], a00);
      a00 = MF(ah0, b1h[s], a00);
      a01 = MF(al1, b1h[s], a01);
      a01 = MF(ah1, b1l[s], a01);
      a01 = MF(ah1, b1h[s], a01);
    }
    __syncthreads();  // all x reads done; h planes overlay x region

    // ---- h = relu(acc + b1) -> hi/lo planes ----
    {
      const int c = wid * 16 + l15;
#pragma unroll
      for (int reg = 0; reg < 4; reg++) {
        int row = g * 4 + reg;
        float v = fmaxf(a00[reg] + bias1, 0.f);
        u16 hi = f2bf(v);
        int idx = row * E_HS + c;
        sm[idx] = hi; sm[E_LO + idx] = f2bf(v - bf2f(hi));
        row += 16;
        v = fmaxf(a01[reg] + bias1, 0.f);
        hi = f2bf(v);
        idx = row * E_HS + c;
        sm[idx] = hi; sm[E_LO + idx] = f2bf(v - bf2f(hi));
      }
    }
    __syncthreads();

    // ---- layer 2: 32x64 = h(32x128) @ W2 ----
    f4 a2 = {0.f, 0.f, 0.f, 0.f};
    const int rt2 = wid >> 2;
#pragma unroll
    for (int s = 0; s < 4; s++) {
      const int idx = (rt2 * 16 + l15) * E_HS + s * 32 + g * 8;
      const u16x8 ah = *(const u16x8*)&sm[idx];
      const u16x8 al = *(const u16x8*)&sm[E_LO + idx];
      a2 = MF(al, b2h[s], a2);
      a2 = MF(ah, b2l[s], a2);
      a2 = MF(ah, b2h[s], a2);
    }
    {
      float* ob = (float*)&sm[E_OB];
#pragma unroll
      for (int reg = 0; reg < 4; reg++) {
        const int row = rt2 * 16 + g * 4 + reg;
        ob[row * 64 + (wid & 3) * 16 + l15] = fmaxf(a2[reg] + bias2, 0.f);
      }
    }
    __syncthreads();

    // ---- LayerNorm + store + scatter-add ----
    if (t < 256) {
      const float* ob = (const float*)&sm[E_OB];
      const int row = t >> 3, p = t & 7;
      const f4 v0 = *(const f4*)&ob[row * 64 + p * 8];
      const f4 v1 = *(const f4*)&ob[row * 64 + p * 8 + 4];
      float s = 0.f, s2 = 0.f;
#pragma unroll
      for (int j = 0; j < 4; j++) {
        s += v0[j] + v1[j];
        s2 += v0[j] * v0[j] + v1[j] * v1[j];
      }
      s += __shfl_xor(s, 1);  s += __shfl_xor(s, 2);  s += __shfl_xor(s, 4);
      s2 += __shfl_xor(s2, 1); s2 += __shfl_xor(s2, 2); s2 += __shfl_xor(s2, 4);
      const float mu = s * (1.f / 64.f);
      const float var = s2 * (1.f / 64.f) - mu * mu;
      const float rstd = rsqrtf(var + 1e-5f);
      f4 o0, o1;
#pragma unroll
      for (int j = 0; j < 4; j++) {
        o0[j] = (v0[j] - mu) * rstd * ga0[j] + be0[j];
        o1[j] = (v1[j] - mu) * rstd * ga1[j] + be1[j];
      }
      const long e = ebase + row;
      float* op = edge_out + (size_t)e * 64 + p * 8;
      *(f4*)op = o0;
      *(f4*)(op + 4) = o1;
      const int col = eidx[NE + e];
      float* ap = agg + (size_t)col * 64 + p * 8;
#pragma unroll
      for (int j = 0; j < 4; j++) {
        atomicAdd(&ap[j], o0[j]);
        atomicAdd(&ap[j + 4], o1[j]);
      }
    }
  }
}

// ---- node kernel LDS (u16 units) ----
// x/h: 32 rows, 128 cols, stride 136; hi [0,4352), lo [4352,8704)
// ob: fp32 32x64 at u16 ofs 8704 (4096 u16) -> total 12800 u16 = 25600 B
#define N_XS 136
#define N_LO 4352
#define N_OB 8704

__global__ __launch_bounds__(512, 2)
void node_mlp_kernel(const float* __restrict__ node_attr,
                     const float* __restrict__ agg,
                     const float* __restrict__ W1, const float* __restrict__ b1,
                     const float* __restrict__ W2, const float* __restrict__ b2,
                     const float* __restrict__ gamma, const float* __restrict__ beta,
                     float* __restrict__ node_out, int ntiles) {
  __shared__ __align__(16) u16 sm[12800];
  const int t = threadIdx.x;
  const int wid = t >> 6, lane = t & 63, g = lane >> 4, l15 = lane & 15;

  u16x8 b1h[4], b1l[4], b2h[4], b2l[4];
  {
    const int c1 = wid * 16 + l15;
#pragma unroll
    for (int s = 0; s < 4; s++) {
      u16x8 th, tl;
#pragma unroll
      for (int i = 0; i < 8; i++) {
        float w = W1[(s * 32 + g * 8 + i) * 128 + c1];
        u16 hi = f2bf(w);
        th[i] = hi; tl[i] = f2bf(w - bf2f(hi));
      }
      b1h[s] = th; b1l[s] = tl;
    }
    const int c2 = (wid & 3) * 16 + l15;
#pragma unroll
    for (int s = 0; s < 4; s++) {
      u16x8 th, tl;
#pragma unroll
      for (int i = 0; i < 8; i++) {
        float w = W2[(s * 32 + g * 8 + i) * 64 + c2];
        u16 hi = f2bf(w);
        th[i] = hi; tl[i] = f2bf(w - bf2f(hi));
      }
      b2h[s] = th; b2l[s] = tl;
    }
  }
  const float bias1 = b1[wid * 16 + l15];
  const float bias2 = b2[(wid & 3) * 16 + l15];
  f4 ga0 = {}, ga1 = {}, be0 = {}, be1 = {};
  if (t < 256) {
    const int p = t & 7;
    ga0 = *(const f4*)&gamma[p * 8]; ga1 = *(const f4*)&gamma[p * 8 + 4];
    be0 = *(const f4*)&beta[p * 8];  be1 = *(const f4*)&beta[p * 8 + 4];
  }

  for (int tile = blockIdx.x; tile < ntiles; tile += gridDim.x) {
    const long nbase = (long)tile * 32;
    __syncthreads();

    // ---- gather x = [node_attr | agg] -> hi/lo planes ----
#pragma unroll
    for (int i = 0; i < 2; i++) {
      const int f = t + 512 * i;
      const int r = f >> 5, q = f & 31;
      long n = nbase + r;
      if (n >= NN) n = NN - 1;  // clamp loads; stores guarded
      const float* src = (q < 16) ? node_attr + (size_t)n * 64 + q * 4
                                  : agg + (size_t)n * 64 + (q - 16) * 4;
      const f4 v = *(const f4*)src;
      u16x4 h, l;
#pragma unroll
      for (int j = 0; j < 4; j++) {
        u16 hi = f2bf(v[j]); h[j] = hi; l[j] = f2bf(v[j] - bf2f(hi));
      }
      const int idx = r * N_XS + 4 * q;
      *(u16x4*)&sm[idx] = h;
      *(u16x4*)&sm[N_LO + idx] = l;
    }
    __syncthreads();

    // ---- layer 1 ----
    f4 a00 = {0.f, 0.f, 0.f, 0.f}, a01 = {0.f, 0.f, 0.f, 0.f};
#pragma unroll
    for (int s = 0; s < 4; s++) {
      const int i0 = l15 * N_XS + s * 32 + g * 8;
      const u16x8 ah0 = *(const u16x8*)&sm[i0];
      const u16x8 al0 = *(const u16x8*)&sm[N_LO + i0];
      const int i1 = i0 + 16 * N_XS;
      const u16x8 ah1 = *(const u16x8*)&sm[i1];
      const u16x8 al1 = *(const u16x8*)&sm[N_LO + i1];
      a00 = MF(al0, b1h[s], a00);
      a00 = MF(ah0, b1l[s], a00);
      a00 = MF(ah0, b1h[s], a00);
      a01 = MF(al1, b1h[s], a01);
      a01 = MF(ah1, b1l[s], a01);
      a01 = MF(ah1, b1h[s], a01);
    }
    __syncthreads();

    {
      const int c = wid * 16 + l15;
#pragma unroll
      for (int reg = 0; reg < 4; reg++) {
        int row = g * 4 + reg;
        float v = fmaxf(a00[reg] + bias1, 0.f);
        u16 hi = f2bf(v);
        int idx = row * N_XS + c;
        sm[idx] = hi; sm[N_LO + idx] = f2bf(v - bf2f(hi));
        row += 16;
        v = fmaxf(a01[reg] + bias1, 0.f);
        hi = f2bf(v);
        idx = row * N_XS + c;
        sm[idx] = hi; sm[N_LO + idx] = f2bf(v - bf2f(hi));
      }
    }
    __syncthreads();

    // ---- layer 2 ----
    f4 a2 = {0.f, 0.f, 0.f, 0.f};
    const int rt2 = wid >> 2;
#pragma unroll
    for (int s = 0; s < 4; s++) {
      const int idx = (rt2 * 16 + l15) * N_XS + s * 32 + g * 8;
      const u16x8 ah = *(const u16x8*)&sm[idx];
      const u16x8 al = *(const u16x8*)&sm[N_LO + idx];
      a2 = MF(al, b2h[s], a2);
      a2 = MF(ah, b2l[s], a2);
      a2 = MF(ah, b2h[s], a2);
    }
    {
      float* ob = (float*)&sm[N_OB];
#pragma unroll
      for (int reg = 0; reg < 4; reg++) {
        const int row = rt2 * 16 + g * 4 + reg;
        ob[row * 64 + (wid & 3) * 16 + l15] = fmaxf(a2[reg] + bias2, 0.f);
      }
    }
    __syncthreads();

    // ---- LayerNorm + store ----
    if (t < 256) {
      const float* ob = (const float*)&sm[N_OB];
      const int row = t >> 3, p = t & 7;
      const f4 v0 = *(const f4*)&ob[row * 64 + p * 8];
      const f4 v1 = *(const f4*)&ob[row * 64 + p * 8 + 4];
      float s = 0.f, s2 = 0.f;
#pragma unroll
      for (int j = 0; j < 4; j++) {
        s += v0[j] + v1[j];
        s2 += v0[j] * v0[j] + v1[j] * v1[j];
      }
      s += __shfl_xor(s, 1);  s += __shfl_xor(s, 2);  s += __shfl_xor(s, 4);
      s2 += __shfl_xor(s2, 1); s2 += __shfl_xor(s2, 2); s2 += __shfl_xor(s2, 4);
      const float mu = s * (1.f / 64.f);
      const float var = s2 * (1.f / 64.f) - mu * mu;
      const float rstd = rsqrtf(var + 1e-5f);
      const long n = nbase + row;
      if (n < NN) {
        f4 o0, o1;
#pragma unroll
        for (int j = 0; j < 4; j++) {
          o0[j] = (v0[j] - mu) * rstd * ga0[j] + be0[j];
          o1[j] = (v1[j] - mu) * rstd * ga1[j] + be1[j];
        }
        float* op = node_out + (size_t)n * 64 + p * 8;
        *(f4*)op = o0;
        *(f4*)(op + 4) = o1;
      }
    }
  }
}

extern "C" void kernel_launch(void* const* d_in, const int* in_sizes, int n_in,
                              void* d_out, int out_size, void* d_ws, size_t ws_size,
                              hipStream_t stream) {
  const float* edge_attr = (const float*)d_in[0];
  const float* node_attr = (const float*)d_in[1];
  const int* eidx = (const int*)d_in[2];
  // d_in[3] = batch (unused)
  const float* eW1 = (const float*)d_in[4];
  const float* eb1 = (const float*)d_in[5];
  const float* eW2 = (const float*)d_in[6];
  const float* eb2 = (const float*)d_in[7];
  const float* eg = (const float*)d_in[8];
  const float* ebt = (const float*)d_in[9];
  const float* nW1 = (const float*)d_in[10];
  const float* nb1 = (const float*)d_in[11];
  const float* nW2 = (const float*)d_in[12];
  const float* nb2 = (const float*)d_in[13];
  const float* ng = (const float*)d_in[14];
  const float* nbt = (const float*)d_in[15];

  float* out_edge = (float*)d_out;
  float* out_node = out_edge + (size_t)NE * 64;
  float* agg = (float*)d_ws;  // [NN][64] accumulator

  const int n4 = NN * 64 / 4;
  zero_kernel<<<(n4 + 255) / 256, 256, 0, stream>>>(agg, n4);

  const int etiles = NE / 32;         // 25000
  const int ntiles = (NN + 31) / 32;  // 1563
  edge_mlp_kernel<<<1024, 512, 0, stream>>>(edge_attr, node_attr, eidx,
                                            eW1, eb1, eW2, eb2, eg, ebt,
                                            out_edge, agg, etiles);
  node_mlp_kernel<<<512, 512, 0, stream>>>(node_attr, agg,
                                           nW1, nb1, nW2, nb2, ng, nbt,
                                           out_node, ntiles);
}

// Round 8
// 933.865 us; speedup vs baseline: 3.5273x; 1.7454x over previous
//
#include <hip/hip_runtime.h>

typedef float f4 __attribute__((ext_vector_type(4)));
typedef __bf16 bf16x8 __attribute__((ext_vector_type(8)));
typedef unsigned short u16;
typedef u16 u16x4 __attribute__((ext_vector_type(4)));
typedef u16 u16x8 __attribute__((ext_vector_type(8)));

#define NE 800000
#define NN 50000

static __device__ __forceinline__ f4 MF(u16x8 a, u16x8 b, f4 c) {
  return __builtin_amdgcn_mfma_f32_16x16x32_bf16(
      __builtin_bit_cast(bf16x8, a), __builtin_bit_cast(bf16x8, b), c, 0, 0, 0);
}

static __device__ __forceinline__ u16 f2bf(float x) {
  unsigned u = __builtin_bit_cast(unsigned, x);
  return (u16)((u + 0x7FFFu + ((u >> 16) & 1u)) >> 16);
}
static __device__ __forceinline__ float bf2f(u16 h) {
  return __builtin_bit_cast(float, ((unsigned)h) << 16);
}

// ---------------- CSR build ----------------
__global__ void zero_int_kernel(int* __restrict__ p, int n) {
  int i = blockIdx.x * blockDim.x + threadIdx.x;
  if (i < n) p[i] = 0;
}

__global__ void hist_kernel(const int* __restrict__ eidx, int* __restrict__ deg) {
  int e = blockIdx.x * blockDim.x + threadIdx.x;
  if (e < NE) atomicAdd(&deg[eidx[NE + e]], 1);
}

__global__ __launch_bounds__(1024)
void scan_kernel(const int* __restrict__ deg, int* __restrict__ offsets,
                 int* __restrict__ cur) {
  __shared__ int buf[2][1024];
  const int t = threadIdx.x;
  const int CH = (NN + 1023) / 1024;  // 49
  const int s = t * CH;
  const int e = (s + CH < NN) ? s + CH : NN;
  int sum = 0;
  for (int i = s; i < e; i++) sum += deg[i];
  buf[0][t] = sum;
  __syncthreads();
  int src = 0;
  for (int d = 1; d < 1024; d <<= 1) {
    int v = buf[src][t];
    if (t >= d) v += buf[src][t - d];
    buf[src ^ 1][t] = v;
    src ^= 1;
    __syncthreads();
  }
  int run = buf[src][t] - sum;  // exclusive prefix
  for (int i = s; i < e; i++) {
    offsets[i] = run;
    cur[i] = run;
    run += deg[i];
  }
  if (e == NN) offsets[NN] = run;  // all covering threads write NE identically
}

__global__ void scatter_kernel(const int* __restrict__ eidx, int* __restrict__ cur,
                               int* __restrict__ elist) {
  int e = blockIdx.x * blockDim.x + threadIdx.x;
  if (e < NE) {
    int slot = atomicAdd(&cur[eidx[NE + e]], 1);
    elist[slot] = e;
  }
}

// ---- edge kernel LDS (u16 units) ----
#define E_XS 200
#define E_HS 136
#define E_LO 6400
#define E_OB 12800

__global__ __launch_bounds__(512, 2)
void edge_mlp_kernel(const float* __restrict__ edge_attr,
                     const float* __restrict__ node_attr,
                     const int* __restrict__ eidx,
                     const float* __restrict__ W1, const float* __restrict__ b1,
                     const float* __restrict__ W2, const float* __restrict__ b2,
                     const float* __restrict__ gamma, const float* __restrict__ beta,
                     float* __restrict__ edge_out, int ntiles) {
  __shared__ __align__(16) u16 sm[16896];
  const int t = threadIdx.x;
  const int wid = t >> 6, lane = t & 63, g = lane >> 4, l15 = lane & 15;

  u16x8 b1h[6], b1l[6], b2h[4], b2l[4];
  {
    const int c1 = wid * 16 + l15;
#pragma unroll
    for (int s = 0; s < 6; s++) {
      u16x8 th, tl;
#pragma unroll
      for (int i = 0; i < 8; i++) {
        float w = W1[(s * 32 + g * 8 + i) * 128 + c1];
        u16 hi = f2bf(w);
        th[i] = hi; tl[i] = f2bf(w - bf2f(hi));
      }
      b1h[s] = th; b1l[s] = tl;
    }
    const int c2 = (wid & 3) * 16 + l15;
#pragma unroll
    for (int s = 0; s < 4; s++) {
      u16x8 th, tl;
#pragma unroll
      for (int i = 0; i < 8; i++) {
        float w = W2[(s * 32 + g * 8 + i) * 64 + c2];
        u16 hi = f2bf(w);
        th[i] = hi; tl[i] = f2bf(w - bf2f(hi));
      }
      b2h[s] = th; b2l[s] = tl;
    }
  }
  const float bias1 = b1[wid * 16 + l15];
  const float bias2 = b2[(wid & 3) * 16 + l15];
  f4 ga0 = {}, ga1 = {}, be0 = {}, be1 = {};
  if (t < 256) {
    const int p = t & 7;
    ga0 = *(const f4*)&gamma[p * 8]; ga1 = *(const f4*)&gamma[p * 8 + 4];
    be0 = *(const f4*)&beta[p * 8];  be1 = *(const f4*)&beta[p * 8 + 4];
  }

  for (int tile = blockIdx.x; tile < ntiles; tile += gridDim.x) {
    const long ebase = (long)tile * 32;
    __syncthreads();

#pragma unroll
    for (int i = 0; i < 3; i++) {
      const int f = t + 512 * i;
      const int r = f / 48, q = f - r * 48;
      const long e = ebase + r;
      const float* src;
      if (q < 16)      src = node_attr + (size_t)eidx[NE + e] * 64 + q * 4;
      else if (q < 32) src = node_attr + (size_t)eidx[e] * 64 + (q - 16) * 4;
      else             src = edge_attr + (size_t)e * 64 + (q - 32) * 4;
      const f4 v = *(const f4*)src;
      u16x4 h, l;
#pragma unroll
      for (int j = 0; j < 4; j++) {
        u16 hi = f2bf(v[j]); h[j] = hi; l[j] = f2bf(v[j] - bf2f(hi));
      }
      const int idx = r * E_XS + 4 * q;
      *(u16x4*)&sm[idx] = h;
      *(u16x4*)&sm[E_LO + idx] = l;
    }
    __syncthreads();

    f4 a00 = {0.f, 0.f, 0.f, 0.f}, a01 = {0.f, 0.f, 0.f, 0.f};
#pragma unroll
    for (int s = 0; s < 6; s++) {
      const int i0 = l15 * E_XS + s * 32 + g * 8;
      const u16x8 ah0 = *(const u16x8*)&sm[i0];
      const u16x8 al0 = *(const u16x8*)&sm[E_LO + i0];
      const int i1 = i0 + 16 * E_XS;
      const u16x8 ah1 = *(const u16x8*)&sm[i1];
      const u16x8 al1 = *(const u16x8*)&sm[E_LO + i1];
      a00 = MF(al0, b1h[s], a00);
      a00 = MF(ah0, b1l[s], a00);
      a00 = MF(ah0, b1h[s], a00);
      a01 = MF(al1, b1h[s], a01);
      a01 = MF(ah1, b1l[s], a01);
      a01 = MF(ah1, b1h[s], a01);
    }
    __syncthreads();

    {
      const int c = wid * 16 + l15;
#pragma unroll
      for (int reg = 0; reg < 4; reg++) {
        int row = g * 4 + reg;
        float v = fmaxf(a00[reg] + bias1, 0.f);
        u16 hi = f2bf(v);
        int idx = row * E_HS + c;
        sm[idx] = hi; sm[E_LO + idx] = f2bf(v - bf2f(hi));
        row += 16;
        v = fmaxf(a01[reg] + bias1, 0.f);
        hi = f2bf(v);
        idx = row * E_HS + c;
        sm[idx] = hi; sm[E_LO + idx] = f2bf(v - bf2f(hi));
      }
    }
    __syncthreads();

    f4 a2 = {0.f, 0.f, 0.f, 0.f};
    const int rt2 = wid >> 2;
#pragma unroll
    for (int s = 0; s < 4; s++) {
      const int idx = (rt2 * 16 + l15) * E_HS + s * 32 + g * 8;
      const u16x8 ah = *(const u16x8*)&sm[idx];
      const u16x8 al = *(const u16x8*)&sm[E_LO + idx];
      a2 = MF(al, b2h[s], a2);
      a2 = MF(ah, b2l[s], a2);
      a2 = MF(ah, b2h[s], a2);
    }
    {
      float* ob = (float*)&sm[E_OB];
#pragma unroll
      for (int reg = 0; reg < 4; reg++) {
        const int row = rt2 * 16 + g * 4 + reg;
        ob[row * 64 + (wid & 3) * 16 + l15] = fmaxf(a2[reg] + bias2, 0.f);
      }
    }
    __syncthreads();

    if (t < 256) {
      const float* ob = (const float*)&sm[E_OB];
      const int row = t >> 3, p = t & 7;
      const f4 v0 = *(const f4*)&ob[row * 64 + p * 8];
      const f4 v1 = *(const f4*)&ob[row * 64 + p * 8 + 4];
      float s = 0.f, s2 = 0.f;
#pragma unroll
      for (int j = 0; j < 4; j++) {
        s += v0[j] + v1[j];
        s2 += v0[j] * v0[j] + v1[j] * v1[j];
      }
      s += __shfl_xor(s, 1);  s += __shfl_xor(s, 2);  s += __shfl_xor(s, 4);
      s2 += __shfl_xor(s2, 1); s2 += __shfl_xor(s2, 2); s2 += __shfl_xor(s2, 4);
      const float mu = s * (1.f / 64.f);
      const float var = s2 * (1.f / 64.f) - mu * mu;
      const float rstd = rsqrtf(var + 1e-5f);
      f4 o0, o1;
#pragma unroll
      for (int j = 0; j < 4; j++) {
        o0[j] = (v0[j] - mu) * rstd * ga0[j] + be0[j];
        o1[j] = (v1[j] - mu) * rstd * ga1[j] + be1[j];
      }
      const long e = ebase + row;
      float* op = edge_out + (size_t)e * 64 + p * 8;
      *(f4*)op = o0;
      *(f4*)(op + 4) = o1;
    }
  }
}

// ---- node kernel LDS (u16 units) ----
#define N_XS 136
#define N_LO 4352
#define N_OB 8704

__global__ __launch_bounds__(512, 2)
void node_mlp_kernel(const float* __restrict__ node_attr,
                     const float* __restrict__ edge_out,
                     const int* __restrict__ offsets,
                     const int* __restrict__ elist,
                     const float* __restrict__ W1, const float* __restrict__ b1,
                     const float* __restrict__ W2, const float* __restrict__ b2,
                     const float* __restrict__ gamma, const float* __restrict__ beta,
                     float* __restrict__ node_out, int ntiles) {
  __shared__ __align__(16) u16 sm[12800];
  const int t = threadIdx.x;
  const int wid = t >> 6, lane = t & 63, g = lane >> 4, l15 = lane & 15;

  u16x8 b1h[4], b1l[4], b2h[4], b2l[4];
  {
    const int c1 = wid * 16 + l15;
#pragma unroll
    for (int s = 0; s < 4; s++) {
      u16x8 th, tl;
#pragma unroll
      for (int i = 0; i < 8; i++) {
        float w = W1[(s * 32 + g * 8 + i) * 128 + c1];
        u16 hi = f2bf(w);
        th[i] = hi; tl[i] = f2bf(w - bf2f(hi));
      }
      b1h[s] = th; b1l[s] = tl;
    }
    const int c2 = (wid & 3) * 16 + l15;
#pragma unroll
    for (int s = 0; s < 4; s++) {
      u16x8 th, tl;
#pragma unroll
      for (int i = 0; i < 8; i++) {
        float w = W2[(s * 32 + g * 8 + i) * 64 + c2];
        u16 hi = f2bf(w);
        th[i] = hi; tl[i] = f2bf(w - bf2f(hi));
      }
      b2h[s] = th; b2l[s] = tl;
    }
  }
  const float bias1 = b1[wid * 16 + l15];
  const float bias2 = b2[(wid & 3) * 16 + l15];
  f4 ga0 = {}, ga1 = {}, be0 = {}, be1 = {};
  if (t < 256) {
    const int p = t & 7;
    ga0 = *(const f4*)&gamma[p * 8]; ga1 = *(const f4*)&gamma[p * 8 + 4];
    be0 = *(const f4*)&beta[p * 8];  be1 = *(const f4*)&beta[p * 8 + 4];
  }

  for (int tile = blockIdx.x; tile < ntiles; tile += gridDim.x) {
    const long nbase = (long)tile * 32;
    __syncthreads();

    // ---- gather x = [node_attr | csr-sum(edge_out)] -> hi/lo planes ----
    {
      const int r = t >> 4, q = t & 15;  // 16 lanes per node row, f4 each
      const long n = nbase + r;
      f4 va = {0.f, 0.f, 0.f, 0.f}, vb = {0.f, 0.f, 0.f, 0.f};
      if (n < NN) {
        va = *(const f4*)&node_attr[(size_t)n * 64 + q * 4];
        const int o0 = offsets[n], o1 = offsets[n + 1];
        for (int i = o0; i < o1; i++) {
          const int e = elist[i];
          const f4 u = *(const f4*)&edge_out[(size_t)e * 64 + q * 4];
#pragma unroll
          for (int j = 0; j < 4; j++) vb[j] += u[j];
        }
      }
      u16x4 ha, la, hb, lb;
#pragma unroll
      for (int j = 0; j < 4; j++) {
        u16 hi = f2bf(va[j]); ha[j] = hi; la[j] = f2bf(va[j] - bf2f(hi));
        hi = f2bf(vb[j]);     hb[j] = hi; lb[j] = f2bf(vb[j] - bf2f(hi));
      }
      const int ia = r * N_XS + 4 * q;
      *(u16x4*)&sm[ia] = ha;
      *(u16x4*)&sm[N_LO + ia] = la;
      const int ib = r * N_XS + 64 + 4 * q;
      *(u16x4*)&sm[ib] = hb;
      *(u16x4*)&sm[N_LO + ib] = lb;
    }
    __syncthreads();

    f4 a00 = {0.f, 0.f, 0.f, 0.f}, a01 = {0.f, 0.f, 0.f, 0.f};
#pragma unroll
    for (int s = 0; s < 4; s++) {
      const int i0 = l15 * N_XS + s * 32 + g * 8;
      const u16x8 ah0 = *(const u16x8*)&sm[i0];
      const u16x8 al0 = *(const u16x8*)&sm[N_LO + i0];
      const int i1 = i0 + 16 * N_XS;
      const u16x8 ah1 = *(const u16x8*)&sm[i1];
      const u16x8 al1 = *(const u16x8*)&sm[N_LO + i1];
      a00 = MF(al0, b1h[s], a00);
      a00 = MF(ah0, b1l[s], a00);
      a00 = MF(ah0, b1h[s], a00);
      a01 = MF(al1, b1h[s], a01);
      a01 = MF(ah1, b1l[s], a01);
      a01 = MF(ah1, b1h[s], a01);
    }
    __syncthreads();

    {
      const int c = wid * 16 + l15;
#pragma unroll
      for (int reg = 0; reg < 4; reg++) {
        int row = g * 4 + reg;
        float v = fmaxf(a00[reg] + bias1, 0.f);
        u16 hi = f2bf(v);
        int idx = row * N_XS + c;
        sm[idx] = hi; sm[N_LO + idx] = f2bf(v - bf2f(hi));
        row += 16;
        v = fmaxf(a01[reg] + bias1, 0.f);
        hi = f2bf(v);
        idx = row * N_XS + c;
        sm[idx] = hi; sm[N_LO + idx] = f2bf(v - bf2f(hi));
      }
    }
    __syncthreads();

    f4 a2 = {0.f, 0.f, 0.f, 0.f};
    const int rt2 = wid >> 2;
#pragma unroll
    for (int s = 0; s < 4; s++) {
      const int idx = (rt2 * 16 + l15) * N_XS + s * 32 + g * 8;
      const u16x8 ah = *(const u16x8*)&sm[idx];
      const u16x8 al = *(const u16x8*)&sm[N_LO + idx];
      a2 = MF(al, b2h[s], a2);
      a2 = MF(ah, b2l[s], a2);
      a2 = MF(ah, b2h[s], a2);
    }
    {
      float* ob = (float*)&sm[N_OB];
#pragma unroll
      for (int reg = 0; reg < 4; reg++) {
        const int row = rt2 * 16 + g * 4 + reg;
        ob[row * 64 + (wid & 3) * 16 + l15] = fmaxf(a2[reg] + bias2, 0.f);
      }
    }
    __syncthreads();

    if (t < 256) {
      const float* ob = (const float*)&sm[N_OB];
      const int row = t >> 3, p = t & 7;
      const f4 v0 = *(const f4*)&ob[row * 64 + p * 8];
      const f4 v1 = *(const f4*)&ob[row * 64 + p * 8 + 4];
      float s = 0.f, s2 = 0.f;
#pragma unroll
      for (int j = 0; j < 4; j++) {
        s += v0[j] + v1[j];
        s2 += v0[j] * v0[j] + v1[j] * v1[j];
      }
      s += __shfl_xor(s, 1);  s += __shfl_xor(s, 2);  s += __shfl_xor(s, 4);
      s2 += __shfl_xor(s2, 1); s2 += __shfl_xor(s2, 2); s2 += __shfl_xor(s2, 4);
      const float mu = s * (1.f / 64.f);
      const float var = s2 * (1.f / 64.f) - mu * mu;
      const float rstd = rsqrtf(var + 1e-5f);
      const long n = nbase + row;
      if (n < NN) {
        f4 o0, o1;
#pragma unroll
        for (int j = 0; j < 4; j++) {
          o0[j] = (v0[j] - mu) * rstd * ga0[j] + be0[j];
          o1[j] = (v1[j] - mu) * rstd * ga1[j] + be1[j];
        }
        float* op = node_out + (size_t)n * 64 + p * 8;
        *(f4*)op = o0;
        *(f4*)(op + 4) = o1;
      }
    }
  }
}

extern "C" void kernel_launch(void* const* d_in, const int* in_sizes, int n_in,
                              void* d_out, int out_size, void* d_ws, size_t ws_size,
                              hipStream_t stream) {
  const float* edge_attr = (const float*)d_in[0];
  const float* node_attr = (const float*)d_in[1];
  const int* eidx = (const int*)d_in[2];
  // d_in[3] = batch (unused)
  const float* eW1 = (const float*)d_in[4];
  const float* eb1 = (const float*)d_in[5];
  const float* eW2 = (const float*)d_in[6];
  const float* eb2 = (const float*)d_in[7];
  const float* eg = (const float*)d_in[8];
  const float* ebt = (const float*)d_in[9];
  const float* nW1 = (const float*)d_in[10];
  const float* nb1 = (const float*)d_in[11];
  const float* nW2 = (const float*)d_in[12];
  const float* nb2 = (const float*)d_in[13];
  const float* ng = (const float*)d_in[14];
  const float* nbt = (const float*)d_in[15];

  float* out_edge = (float*)d_out;
  float* out_node = out_edge + (size_t)NE * 64;

  // workspace: CSR arrays (ints)
  int* deg = (int*)d_ws;
  int* offsets = deg + NN;        // NN+1 entries
  int* cur = offsets + NN + 1;
  int* elist = cur + NN;          // NE entries

  zero_int_kernel<<<(NN + 255) / 256, 256, 0, stream>>>(deg, NN);
  hist_kernel<<<(NE + 255) / 256, 256, 0, stream>>>(eidx, deg);
  scan_kernel<<<1, 1024, 0, stream>>>(deg, offsets, cur);
  scatter_kernel<<<(NE + 255) / 256, 256, 0, stream>>>(eidx, cur, elist);

  const int etiles = NE / 32;         // 25000
  const int ntiles = (NN + 31) / 32;  // 1563
  edge_mlp_kernel<<<1024, 512, 0, stream>>>(edge_attr, node_attr, eidx,
                                            eW1, eb1, eW2, eb2, eg, ebt,
                                            out_edge, etiles);
  node_mlp_kernel<<<512, 512, 0, stream>>>(node_attr, out_edge, offsets, elist,
                                           nW1, nb1, nW2, nb2, ng, nbt,
                                           out_node, ntiles);
}

// Round 9
// 755.515 us; speedup vs baseline: 4.3599x; 1.2361x over previous
//
#include <hip/hip_runtime.h>

typedef float f4 __attribute__((ext_vector_type(4)));
typedef _Float16 f16;
typedef f16 f16x8 __attribute__((ext_vector_type(8)));
typedef unsigned short u16;
typedef u16 u16x4 __attribute__((ext_vector_type(4)));
typedef u16 u16x8 __attribute__((ext_vector_type(8)));

#define NE 800000
#define NN 50000

static __device__ __forceinline__ f4 MF(u16x8 a, u16x8 b, f4 c) {
  return __builtin_amdgcn_mfma_f32_16x16x32_f16(
      __builtin_bit_cast(f16x8, a), __builtin_bit_cast(f16x8, b), c, 0, 0, 0);
}
static __device__ __forceinline__ u16 f2h(float x) {
  return __builtin_bit_cast(u16, (f16)x);
}

// ---------------- CSR build ----------------
__global__ void zero_int_kernel(int* __restrict__ p, int n) {
  int i = blockIdx.x * blockDim.x + threadIdx.x;
  if (i < n) p[i] = 0;
}

__global__ void hist_kernel(const int* __restrict__ eidx, int* __restrict__ deg) {
  int e = blockIdx.x * blockDim.x + threadIdx.x;
  if (e < NE) atomicAdd(&deg[eidx[NE + e]], 1);
}

__global__ __launch_bounds__(1024)
void scan_kernel(const int* __restrict__ deg, int* __restrict__ offsets,
                 int* __restrict__ cur) {
  __shared__ int buf[2][1024];
  const int t = threadIdx.x;
  const int CH = (NN + 1023) / 1024;  // 49
  const int s = t * CH;
  const int e = (s + CH < NN) ? s + CH : NN;
  int sum = 0;
  for (int i = s; i < e; i++) sum += deg[i];
  buf[0][t] = sum;
  __syncthreads();
  int src = 0;
  for (int d = 1; d < 1024; d <<= 1) {
    int v = buf[src][t];
    if (t >= d) v += buf[src][t - d];
    buf[src ^ 1][t] = v;
    src ^= 1;
    __syncthreads();
  }
  int run = buf[src][t] - sum;  // exclusive prefix
  for (int i = s; i < e; i++) {
    offsets[i] = run;
    cur[i] = run;
    run += deg[i];
  }
  if (e == NN) offsets[NN] = run;
}

__global__ void scatter_kernel(const int* __restrict__ eidx, int* __restrict__ cur,
                               int* __restrict__ elist) {
  int e = blockIdx.x * blockDim.x + threadIdx.x;
  if (e < NE) {
    int slot = atomicAdd(&cur[eidx[NE + e]], 1);
    elist[slot] = e;
  }
}

// ---- edge kernel LDS (u16 units) ----
// x: 32 rows x 192 cols, stride 200 -> [0, 6400)
// h: 32 rows x 128 cols, stride 136 -> [0, 4352)   (overlays x after barrier)
// ob: fp32 32x64 at u16 ofs 6400 (4096 u16) -> total 10496 u16 = 20992 B
#define E_XS 200
#define E_HS 136
#define E_OB 6400

__global__ __launch_bounds__(512, 4)
void edge_mlp_kernel(const float* __restrict__ edge_attr,
                     const float* __restrict__ node_attr,
                     const int* __restrict__ eidx,
                     const float* __restrict__ W1, const float* __restrict__ b1,
                     const float* __restrict__ W2, const float* __restrict__ b2,
                     const float* __restrict__ gamma, const float* __restrict__ beta,
                     float* __restrict__ edge_out, int ntiles) {
  __shared__ __align__(16) u16 sm[10496];
  const int t = threadIdx.x;
  const int wid = t >> 6, lane = t & 63, g = lane >> 4, l15 = lane & 15;
  const int wr1 = wid >> 2, wc1 = wid & 3;  // L1: 16 rows x 32 cols per wave
  const int wr2 = wid & 1, wc2 = wid >> 1;  // L2: 16 rows x 16 cols per wave

  // ---- weight fragments in registers (f16), loaded once ----
  u16x8 b1f[6][2], b2f[4];
#pragma unroll
  for (int s = 0; s < 6; s++)
#pragma unroll
    for (int ci = 0; ci < 2; ci++) {
      const int col = wc1 * 32 + ci * 16 + l15;
      u16x8 th;
#pragma unroll
      for (int i = 0; i < 8; i++) th[i] = f2h(W1[(s * 32 + g * 8 + i) * 128 + col]);
      b1f[s][ci] = th;
    }
#pragma unroll
  for (int s = 0; s < 4; s++) {
    const int col = wc2 * 16 + l15;
    u16x8 th;
#pragma unroll
    for (int i = 0; i < 8; i++) th[i] = f2h(W2[(s * 32 + g * 8 + i) * 64 + col]);
    b2f[s] = th;
  }
  const float bias1_0 = b1[wc1 * 32 + l15];
  const float bias1_1 = b1[wc1 * 32 + 16 + l15];
  const float bias2 = b2[wc2 * 16 + l15];
  f4 ga0 = {}, ga1 = {}, be0 = {}, be1 = {};
  if (t < 256) {
    const int p = t & 7;
    ga0 = *(const f4*)&gamma[p * 8]; ga1 = *(const f4*)&gamma[p * 8 + 4];
    be0 = *(const f4*)&beta[p * 8];  be1 = *(const f4*)&beta[p * 8 + 4];
  }

  for (int tile = blockIdx.x; tile < ntiles; tile += gridDim.x) {
    const long ebase = (long)tile * 32;
    __syncthreads();  // protect LDS reuse across iterations

    // ---- gather x = [recv | send | edge] -> f16 plane ----
#pragma unroll
    for (int i = 0; i < 3; i++) {
      const int f = t + 512 * i;
      const int r = f / 48, q = f - r * 48;
      const long e = ebase + r;
      const float* src;
      if (q < 16)      src = node_attr + (size_t)eidx[NE + e] * 64 + q * 4;
      else if (q < 32) src = node_attr + (size_t)eidx[e] * 64 + (q - 16) * 4;
      else             src = edge_attr + (size_t)e * 64 + (q - 32) * 4;
      const f4 v = *(const f4*)src;
      u16x4 h;
#pragma unroll
      for (int j = 0; j < 4; j++) h[j] = f2h(v[j]);
      *(u16x4*)&sm[r * E_XS + 4 * q] = h;
    }
    __syncthreads();

    // ---- layer 1: per-wave 16x32 tile of h = relu(x @ W1 + b1) ----
    f4 a0 = {0.f, 0.f, 0.f, 0.f}, a1 = {0.f, 0.f, 0.f, 0.f};
#pragma unroll
    for (int s = 0; s < 6; s++) {
      const u16x8 av = *(const u16x8*)&sm[(wr1 * 16 + l15) * E_XS + s * 32 + g * 8];
      a0 = MF(av, b1f[s][0], a0);
      a1 = MF(av, b1f[s][1], a1);
    }
    __syncthreads();  // x reads done; h overlays x

#pragma unroll
    for (int reg = 0; reg < 4; reg++) {
      const int row = wr1 * 16 + 4 * g + reg;
      sm[row * E_HS + wc1 * 32 + l15] = f2h(fmaxf(a0[reg] + bias1_0, 0.f));
      sm[row * E_HS + wc1 * 32 + 16 + l15] = f2h(fmaxf(a1[reg] + bias1_1, 0.f));
    }
    __syncthreads();

    // ---- layer 2: per-wave 16x16 tile of o = relu(h @ W2 + b2) ----
    f4 a2 = {0.f, 0.f, 0.f, 0.f};
#pragma unroll
    for (int s = 0; s < 4; s++) {
      const u16x8 av = *(const u16x8*)&sm[(wr2 * 16 + l15) * E_HS + s * 32 + g * 8];
      a2 = MF(av, b2f[s], a2);
    }
    {
      float* ob = (float*)&sm[E_OB];
#pragma unroll
      for (int reg = 0; reg < 4; reg++) {
        const int row = wr2 * 16 + 4 * g + reg;
        ob[row * 64 + wc2 * 16 + l15] = fmaxf(a2[reg] + bias2, 0.f);
      }
    }
    __syncthreads();

    // ---- LayerNorm + store ----
    if (t < 256) {
      const float* ob = (const float*)&sm[E_OB];
      const int row = t >> 3, p = t & 7;
      const f4 v0 = *(const f4*)&ob[row * 64 + p * 8];
      const f4 v1 = *(const f4*)&ob[row * 64 + p * 8 + 4];
      float s = 0.f, s2 = 0.f;
#pragma unroll
      for (int j = 0; j < 4; j++) {
        s += v0[j] + v1[j];
        s2 += v0[j] * v0[j] + v1[j] * v1[j];
      }
      s += __shfl_xor(s, 1);  s += __shfl_xor(s, 2);  s += __shfl_xor(s, 4);
      s2 += __shfl_xor(s2, 1); s2 += __shfl_xor(s2, 2); s2 += __shfl_xor(s2, 4);
      const float mu = s * (1.f / 64.f);
      const float var = s2 * (1.f / 64.f) - mu * mu;
      const float rstd = rsqrtf(var + 1e-5f);
      f4 o0, o1;
#pragma unroll
      for (int j = 0; j < 4; j++) {
        o0[j] = (v0[j] - mu) * rstd * ga0[j] + be0[j];
        o1[j] = (v1[j] - mu) * rstd * ga1[j] + be1[j];
      }
      float* op = edge_out + (size_t)(ebase + row) * 64 + p * 8;
      *(f4*)op = o0;
      *(f4*)(op + 4) = o1;
    }
  }
}

// ---- node kernel LDS (u16 units) ----
// x/h: 32 rows x 128 cols, stride 136 -> [0, 4352)
// ob: fp32 32x64 at u16 ofs 4352 (4096 u16) -> total 8448 u16 = 16896 B
#define N_XS 136
#define N_OB 4352

__global__ __launch_bounds__(512, 4)
void node_mlp_kernel(const float* __restrict__ node_attr,
                     const float* __restrict__ edge_out,
                     const int* __restrict__ offsets,
                     const int* __restrict__ elist,
                     const float* __restrict__ W1, const float* __restrict__ b1,
                     const float* __restrict__ W2, const float* __restrict__ b2,
                     const float* __restrict__ gamma, const float* __restrict__ beta,
                     float* __restrict__ node_out, int ntiles) {
  __shared__ __align__(16) u16 sm[8448];
  const int t = threadIdx.x;
  const int wid = t >> 6, lane = t & 63, g = lane >> 4, l15 = lane & 15;
  const int wr1 = wid >> 2, wc1 = wid & 3;
  const int wr2 = wid & 1, wc2 = wid >> 1;

  u16x8 b1f[4][2], b2f[4];
#pragma unroll
  for (int s = 0; s < 4; s++)
#pragma unroll
    for (int ci = 0; ci < 2; ci++) {
      const int col = wc1 * 32 + ci * 16 + l15;
      u16x8 th;
#pragma unroll
      for (int i = 0; i < 8; i++) th[i] = f2h(W1[(s * 32 + g * 8 + i) * 128 + col]);
      b1f[s][ci] = th;
    }
#pragma unroll
  for (int s = 0; s < 4; s++) {
    const int col = wc2 * 16 + l15;
    u16x8 th;
#pragma unroll
    for (int i = 0; i < 8; i++) th[i] = f2h(W2[(s * 32 + g * 8 + i) * 64 + col]);
    b2f[s] = th;
  }
  const float bias1_0 = b1[wc1 * 32 + l15];
  const float bias1_1 = b1[wc1 * 32 + 16 + l15];
  const float bias2 = b2[wc2 * 16 + l15];
  f4 ga0 = {}, ga1 = {}, be0 = {}, be1 = {};
  if (t < 256) {
    const int p = t & 7;
    ga0 = *(const f4*)&gamma[p * 8]; ga1 = *(const f4*)&gamma[p * 8 + 4];
    be0 = *(const f4*)&beta[p * 8];  be1 = *(const f4*)&beta[p * 8 + 4];
  }

  for (int tile = blockIdx.x; tile < ntiles; tile += gridDim.x) {
    const long nbase = (long)tile * 32;
    __syncthreads();

    // ---- gather x = [node_attr | csr-sum(edge_out)] -> f16 plane ----
    {
      const int r = t >> 4, q = t & 15;
      const long n = nbase + r;
      f4 va = {0.f, 0.f, 0.f, 0.f}, vb = {0.f, 0.f, 0.f, 0.f};
      if (n < NN) {
        va = *(const f4*)&node_attr[(size_t)n * 64 + q * 4];
        const int o0 = offsets[n], o1 = offsets[n + 1];
        for (int i = o0; i < o1; i++) {
          const int e = elist[i];
          const f4 u = *(const f4*)&edge_out[(size_t)e * 64 + q * 4];
#pragma unroll
          for (int j = 0; j < 4; j++) vb[j] += u[j];
        }
      }
      u16x4 ha, hb;
#pragma unroll
      for (int j = 0; j < 4; j++) { ha[j] = f2h(va[j]); hb[j] = f2h(vb[j]); }
      *(u16x4*)&sm[r * N_XS + 4 * q] = ha;
      *(u16x4*)&sm[r * N_XS + 64 + 4 * q] = hb;
    }
    __syncthreads();

    // ---- layer 1 ----
    f4 a0 = {0.f, 0.f, 0.f, 0.f}, a1 = {0.f, 0.f, 0.f, 0.f};
#pragma unroll
    for (int s = 0; s < 4; s++) {
      const u16x8 av = *(const u16x8*)&sm[(wr1 * 16 + l15) * N_XS + s * 32 + g * 8];
      a0 = MF(av, b1f[s][0], a0);
      a1 = MF(av, b1f[s][1], a1);
    }
    __syncthreads();

#pragma unroll
    for (int reg = 0; reg < 4; reg++) {
      const int row = wr1 * 16 + 4 * g + reg;
      sm[row * N_XS + wc1 * 32 + l15] = f2h(fmaxf(a0[reg] + bias1_0, 0.f));
      sm[row * N_XS + wc1 * 32 + 16 + l15] = f2h(fmaxf(a1[reg] + bias1_1, 0.f));
    }
    __syncthreads();

    // ---- layer 2 ----
    f4 a2 = {0.f, 0.f, 0.f, 0.f};
#pragma unroll
    for (int s = 0; s < 4; s++) {
      const u16x8 av = *(const u16x8*)&sm[(wr2 * 16 + l15) * N_XS + s * 32 + g * 8];
      a2 = MF(av, b2f[s], a2);
    }
    {
      float* ob = (float*)&sm[N_OB];
#pragma unroll
      for (int reg = 0; reg < 4; reg++) {
        const int row = wr2 * 16 + 4 * g + reg;
        ob[row * 64 + wc2 * 16 + l15] = fmaxf(a2[reg] + bias2, 0.f);
      }
    }
    __syncthreads();

    // ---- LayerNorm + store ----
    if (t < 256) {
      const float* ob = (const float*)&sm[N_OB];
      const int row = t >> 3, p = t & 7;
      const f4 v0 = *(const f4*)&ob[row * 64 + p * 8];
      const f4 v1 = *(const f4*)&ob[row * 64 + p * 8 + 4];
      float s = 0.f, s2 = 0.f;
#pragma unroll
      for (int j = 0; j < 4; j++) {
        s += v0[j] + v1[j];
        s2 += v0[j] * v0[j] + v1[j] * v1[j];
      }
      s += __shfl_xor(s, 1);  s += __shfl_xor(s, 2);  s += __shfl_xor(s, 4);
      s2 += __shfl_xor(s2, 1); s2 += __shfl_xor(s2, 2); s2 += __shfl_xor(s2, 4);
      const float mu = s * (1.f / 64.f);
      const float var = s2 * (1.f / 64.f) - mu * mu;
      const float rstd = rsqrtf(var + 1e-5f);
      const long n = nbase + row;
      if (n < NN) {
        f4 o0, o1;
#pragma unroll
        for (int j = 0; j < 4; j++) {
          o0[j] = (v0[j] - mu) * rstd * ga0[j] + be0[j];
          o1[j] = (v1[j] - mu) * rstd * ga1[j] + be1[j];
        }
        float* op = node_out + (size_t)n * 64 + p * 8;
        *(f4*)op = o0;
        *(f4*)(op + 4) = o1;
      }
    }
  }
}

extern "C" void kernel_launch(void* const* d_in, const int* in_sizes, int n_in,
                              void* d_out, int out_size, void* d_ws, size_t ws_size,
                              hipStream_t stream) {
  const float* edge_attr = (const float*)d_in[0];
  const float* node_attr = (const float*)d_in[1];
  const int* eidx = (const int*)d_in[2];
  // d_in[3] = batch (unused)
  const float* eW1 = (const float*)d_in[4];
  const float* eb1 = (const float*)d_in[5];
  const float* eW2 = (const float*)d_in[6];
  const float* eb2 = (const float*)d_in[7];
  const float* eg = (const float*)d_in[8];
  const float* ebt = (const float*)d_in[9];
  const float* nW1 = (const float*)d_in[10];
  const float* nb1 = (const float*)d_in[11];
  const float* nW2 = (const float*)d_in[12];
  const float* nb2 = (const float*)d_in[13];
  const float* ng = (const float*)d_in[14];
  const float* nbt = (const float*)d_in[15];

  float* out_edge = (float*)d_out;
  float* out_node = out_edge + (size_t)NE * 64;

  int* deg = (int*)d_ws;
  int* offsets = deg + NN;
  int* cur = offsets + NN + 1;
  int* elist = cur + NN;

  zero_int_kernel<<<(NN + 255) / 256, 256, 0, stream>>>(deg, NN);
  hist_kernel<<<(NE + 255) / 256, 256, 0, stream>>>(eidx, deg);
  scan_kernel<<<1, 1024, 0, stream>>>(deg, offsets, cur);
  scatter_kernel<<<(NE + 255) / 256, 256, 0, stream>>>(eidx, cur, elist);

  const int etiles = NE / 32;         // 25000
  const int ntiles = (NN + 31) / 32;  // 1563
  edge_mlp_kernel<<<2048, 512, 0, stream>>>(edge_attr, node_attr, eidx,
                                            eW1, eb1, eW2, eb2, eg, ebt,
                                            out_edge, etiles);
  node_mlp_kernel<<<512, 512, 0, stream>>>(node_attr, out_edge, offsets, elist,
                                           nW1, nb1, nW2, nb2, ng, nbt,
                                           out_node, ntiles);
}

// Round 10
// 736.599 us; speedup vs baseline: 4.4719x; 1.0257x over previous
//
#include <hip/hip_runtime.h>

typedef float f4 __attribute__((ext_vector_type(4)));
typedef _Float16 f16;
typedef f16 f16x8 __attribute__((ext_vector_type(8)));
typedef unsigned short u16;
typedef u16 u16x4 __attribute__((ext_vector_type(4)));
typedef u16 u16x8 __attribute__((ext_vector_type(8)));

#define NE 800000
#define NN 50000

static __device__ __forceinline__ f4 MF(u16x8 a, u16x8 b, f4 c) {
  return __builtin_amdgcn_mfma_f32_16x16x32_f16(
      __builtin_bit_cast(f16x8, a), __builtin_bit_cast(f16x8, b), c, 0, 0, 0);
}
static __device__ __forceinline__ u16 f2h(float x) {
  return __builtin_bit_cast(u16, (f16)x);
}

// ---------------- prologue kernels ----------------
__global__ void cvt_kernel(const float* __restrict__ na, u16* __restrict__ nh,
                           int n4) {
  int i = blockIdx.x * blockDim.x + threadIdx.x;
  if (i < n4) {
    const f4 v = ((const f4*)na)[i];
    u16x4 h;
#pragma unroll
    for (int j = 0; j < 4; j++) h[j] = f2h(v[j]);
    ((u16x4*)nh)[i] = h;
  }
}

__global__ void zero_int_kernel(int* __restrict__ p, int n) {
  int i = blockIdx.x * blockDim.x + threadIdx.x;
  if (i < n) p[i] = 0;
}

__global__ void hist_kernel(const int* __restrict__ eidx, int* __restrict__ deg) {
  int e = blockIdx.x * blockDim.x + threadIdx.x;
  if (e < NE) atomicAdd(&deg[eidx[NE + e]], 1);
}

__global__ __launch_bounds__(1024)
void scan_kernel(const int* __restrict__ deg, int* __restrict__ offsets,
                 int* __restrict__ cur) {
  __shared__ int buf[2][1024];
  const int t = threadIdx.x;
  const int CH = (NN + 1023) / 1024;  // 49
  const int s = t * CH;
  const int e = (s + CH < NN) ? s + CH : NN;
  int sum = 0;
  for (int i = s; i < e; i++) sum += deg[i];
  buf[0][t] = sum;
  __syncthreads();
  int src = 0;
  for (int d = 1; d < 1024; d <<= 1) {
    int v = buf[src][t];
    if (t >= d) v += buf[src][t - d];
    buf[src ^ 1][t] = v;
    src ^= 1;
    __syncthreads();
  }
  int run = buf[src][t] - sum;  // exclusive prefix
  for (int i = s; i < e; i++) {
    offsets[i] = run;
    cur[i] = run;
    run += deg[i];
  }
  if (e == NN) offsets[NN] = run;
}

__global__ void scatter_kernel(const int* __restrict__ eidx, int* __restrict__ cur,
                               int* __restrict__ elist) {
  int e = blockIdx.x * blockDim.x + threadIdx.x;
  if (e < NE) {
    int slot = atomicAdd(&cur[eidx[NE + e]], 1);
    elist[slot] = e;
  }
}

// ---- edge kernel LDS (u16 units): x[0,6400) h[6400,10752) ob f32 @10752 ----
#define E_XS 200
#define E_HS 136
#define E_HO 6400
#define E_OB 10752

__global__ __launch_bounds__(512, 2)
void edge_mlp_kernel(const float* __restrict__ edge_attr,
                     const u16* __restrict__ nh,
                     const int* __restrict__ eidx,
                     const float* __restrict__ W1, const float* __restrict__ b1,
                     const float* __restrict__ W2, const float* __restrict__ b2,
                     const float* __restrict__ gamma, const float* __restrict__ beta,
                     float* __restrict__ edge_out, int ntiles) {
  __shared__ __align__(16) u16 sm[14848];
  const int t = threadIdx.x;
  const int wid = t >> 6, lane = t & 63, g = lane >> 4, l15 = lane & 15;
  const int wr1 = wid >> 2, wc1 = wid & 3;  // L1: 16 rows x 32 cols per wave
  const int wr2 = wid & 1, wc2 = wid >> 1;  // L2: 16 rows x 16 cols per wave

  // ---- weight fragments in registers (f16), loaded once ----
  u16x8 b1f[6][2], b2f[4];
#pragma unroll
  for (int s = 0; s < 6; s++)
#pragma unroll
    for (int ci = 0; ci < 2; ci++) {
      const int col = wc1 * 32 + ci * 16 + l15;
      u16x8 th;
#pragma unroll
      for (int i = 0; i < 8; i++) th[i] = f2h(W1[(s * 32 + g * 8 + i) * 128 + col]);
      b1f[s][ci] = th;
    }
#pragma unroll
  for (int s = 0; s < 4; s++) {
    const int col = wc2 * 16 + l15;
    u16x8 th;
#pragma unroll
    for (int i = 0; i < 8; i++) th[i] = f2h(W2[(s * 32 + g * 8 + i) * 64 + col]);
    b2f[s] = th;
  }
  const float bias1_0 = b1[wc1 * 32 + l15];
  const float bias1_1 = b1[wc1 * 32 + 16 + l15];
  const float bias2 = b2[wc2 * 16 + l15];
  f4 ga0 = {}, ga1 = {}, be0 = {}, be1 = {};
  if (t < 256) {
    const int p = t & 7;
    ga0 = *(const f4*)&gamma[p * 8]; ga1 = *(const f4*)&gamma[p * 8 + 4];
    be0 = *(const f4*)&beta[p * 8];  be1 = *(const f4*)&beta[p * 8 + 4];
  }

  // gather slot geometry (3 slots/thread covering 32 rows x 48 u16x4-chunks)
  int rr[3], qq[3];
#pragma unroll
  for (int i = 0; i < 3; i++) {
    const int f = t + 512 * i;
    rr[i] = f / 48;
    qq[i] = f - 48 * rr[i];
  }

  u16x4 gbuf[3];
#define PREFETCH(EBASE)                                                        \
  {                                                                            \
    const long eb_ = (EBASE);                                                  \
    _Pragma("unroll") for (int i = 0; i < 3; i++) {                            \
      const int r_ = rr[i], q_ = qq[i];                                        \
      const long e_ = eb_ + r_;                                                \
      if (q_ < 16) {                                                           \
        const int idx = eidx[NE + e_];                                         \
        gbuf[i] = *(const u16x4*)&nh[(size_t)idx * 64 + q_ * 4];               \
      } else if (q_ < 32) {                                                    \
        const int idx = eidx[e_];                                              \
        gbuf[i] = *(const u16x4*)&nh[(size_t)idx * 64 + (q_ - 16) * 4];        \
      } else {                                                                 \
        const f4 v = *(const f4*)&edge_attr[(size_t)e_ * 64 + (q_ - 32) * 4];  \
        u16x4 h_;                                                              \
        _Pragma("unroll") for (int j = 0; j < 4; j++) h_[j] = f2h(v[j]);       \
        gbuf[i] = h_;                                                          \
      }                                                                        \
    }                                                                          \
  }

  if ((int)blockIdx.x < ntiles) PREFETCH((long)blockIdx.x * 32);

  for (int tile = blockIdx.x; tile < ntiles; tile += gridDim.x) {
    // ---- write prefetched x tile -> LDS ----
#pragma unroll
    for (int i = 0; i < 3; i++) *(u16x4*)&sm[rr[i] * E_XS + 4 * qq[i]] = gbuf[i];
    __syncthreads();  // B1

    // ---- issue next tile's gather (completes under compute) ----
    {
      const int t2 = tile + gridDim.x;
      PREFETCH((long)(t2 < ntiles ? t2 : tile) * 32);
    }

    // ---- layer 1: per-wave 16x32 tile of h = relu(x @ W1 + b1) ----
    f4 a0 = {0.f, 0.f, 0.f, 0.f}, a1 = {0.f, 0.f, 0.f, 0.f};
#pragma unroll
    for (int s = 0; s < 6; s++) {
      const u16x8 av = *(const u16x8*)&sm[(wr1 * 16 + l15) * E_XS + s * 32 + g * 8];
      a0 = MF(av, b1f[s][0], a0);
      a1 = MF(av, b1f[s][1], a1);
    }
#pragma unroll
    for (int reg = 0; reg < 4; reg++) {
      const int row = wr1 * 16 + 4 * g + reg;
      sm[E_HO + row * E_HS + wc1 * 32 + l15] = f2h(fmaxf(a0[reg] + bias1_0, 0.f));
      sm[E_HO + row * E_HS + wc1 * 32 + 16 + l15] = f2h(fmaxf(a1[reg] + bias1_1, 0.f));
    }
    __syncthreads();  // B3: h visible

    // ---- layer 2: per-wave 16x16 tile of o = relu(h @ W2 + b2) ----
    f4 a2 = {0.f, 0.f, 0.f, 0.f};
#pragma unroll
    for (int s = 0; s < 4; s++) {
      const u16x8 av =
          *(const u16x8*)&sm[E_HO + (wr2 * 16 + l15) * E_HS + s * 32 + g * 8];
      a2 = MF(av, b2f[s], a2);
    }
    {
      float* ob = (float*)&sm[E_OB];
#pragma unroll
      for (int reg = 0; reg < 4; reg++) {
        const int row = wr2 * 16 + 4 * g + reg;
        ob[row * 64 + wc2 * 16 + l15] = fmaxf(a2[reg] + bias2, 0.f);
      }
    }
    __syncthreads();  // B4: ob visible (also fences all x reads before next x write)

    // ---- LayerNorm + store ----
    if (t < 256) {
      const float* ob = (const float*)&sm[E_OB];
      const int row = t >> 3, p = t & 7;
      const f4 v0 = *(const f4*)&ob[row * 64 + p * 8];
      const f4 v1 = *(const f4*)&ob[row * 64 + p * 8 + 4];
      float s = 0.f, s2 = 0.f;
#pragma unroll
      for (int j = 0; j < 4; j++) {
        s += v0[j] + v1[j];
        s2 += v0[j] * v0[j] + v1[j] * v1[j];
      }
      s += __shfl_xor(s, 1);  s += __shfl_xor(s, 2);  s += __shfl_xor(s, 4);
      s2 += __shfl_xor(s2, 1); s2 += __shfl_xor(s2, 2); s2 += __shfl_xor(s2, 4);
      const float mu = s * (1.f / 64.f);
      const float var = s2 * (1.f / 64.f) - mu * mu;
      const float rstd = rsqrtf(var + 1e-5f);
      f4 o0, o1;
#pragma unroll
      for (int j = 0; j < 4; j++) {
        o0[j] = (v0[j] - mu) * rstd * ga0[j] + be0[j];
        o1[j] = (v1[j] - mu) * rstd * ga1[j] + be1[j];
      }
      float* op = edge_out + (size_t)((long)tile * 32 + row) * 64 + p * 8;
      *(f4*)op = o0;
      *(f4*)(op + 4) = o1;
    }
  }
#undef PREFETCH
}

// ---- node kernel LDS (u16): x[0,4352) h[4352,8704) ob f32 @8704 ----
#define N_XS 136
#define N_HO 4352
#define N_OB 8704

__global__ __launch_bounds__(512, 2)
void node_mlp_kernel(const u16* __restrict__ nh,
                     const float* __restrict__ edge_out,
                     const int* __restrict__ offsets,
                     const int* __restrict__ elist,
                     const float* __restrict__ W1, const float* __restrict__ b1,
                     const float* __restrict__ W2, const float* __restrict__ b2,
                     const float* __restrict__ gamma, const float* __restrict__ beta,
                     float* __restrict__ node_out, int ntiles) {
  __shared__ __align__(16) u16 sm[12800];
  const int t = threadIdx.x;
  const int wid = t >> 6, lane = t & 63, g = lane >> 4, l15 = lane & 15;
  const int wr1 = wid >> 2, wc1 = wid & 3;
  const int wr2 = wid & 1, wc2 = wid >> 1;

  u16x8 b1f[4][2], b2f[4];
#pragma unroll
  for (int s = 0; s < 4; s++)
#pragma unroll
    for (int ci = 0; ci < 2; ci++) {
      const int col = wc1 * 32 + ci * 16 + l15;
      u16x8 th;
#pragma unroll
      for (int i = 0; i < 8; i++) th[i] = f2h(W1[(s * 32 + g * 8 + i) * 128 + col]);
      b1f[s][ci] = th;
    }
#pragma unroll
  for (int s = 0; s < 4; s++) {
    const int col = wc2 * 16 + l15;
    u16x8 th;
#pragma unroll
    for (int i = 0; i < 8; i++) th[i] = f2h(W2[(s * 32 + g * 8 + i) * 64 + col]);
    b2f[s] = th;
  }
  const float bias1_0 = b1[wc1 * 32 + l15];
  const float bias1_1 = b1[wc1 * 32 + 16 + l15];
  const float bias2 = b2[wc2 * 16 + l15];
  f4 ga0 = {}, ga1 = {}, be0 = {}, be1 = {};
  if (t < 256) {
    const int p = t & 7;
    ga0 = *(const f4*)&gamma[p * 8]; ga1 = *(const f4*)&gamma[p * 8 + 4];
    be0 = *(const f4*)&beta[p * 8];  be1 = *(const f4*)&beta[p * 8 + 4];
  }

  for (int tile = blockIdx.x; tile < ntiles; tile += gridDim.x) {
    const long nbase = (long)tile * 32;
    __syncthreads();  // protect x region across iterations

    // ---- gather x = [node_attr(f16) | csr-sum(edge_out)] ----
    {
      const int r = t >> 4, q = t & 15;
      const long n = nbase + r;
      u16x4 ha = {0, 0, 0, 0};
      f4 vb = {0.f, 0.f, 0.f, 0.f};
      if (n < NN) {
        ha = *(const u16x4*)&nh[(size_t)n * 64 + q * 4];
        const int o0 = offsets[n], o1 = offsets[n + 1];
        int i = o0;
        for (; i + 4 <= o1; i += 4) {
          const int e0 = elist[i], e1 = elist[i + 1];
          const int e2 = elist[i + 2], e3 = elist[i + 3];
          const f4 u0 = *(const f4*)&edge_out[(size_t)e0 * 64 + q * 4];
          const f4 u1 = *(const f4*)&edge_out[(size_t)e1 * 64 + q * 4];
          const f4 u2 = *(const f4*)&edge_out[(size_t)e2 * 64 + q * 4];
          const f4 u3 = *(const f4*)&edge_out[(size_t)e3 * 64 + q * 4];
#pragma unroll
          for (int j = 0; j < 4; j++) vb[j] += (u0[j] + u1[j]) + (u2[j] + u3[j]);
        }
        for (; i < o1; i++) {
          const int e = elist[i];
          const f4 u = *(const f4*)&edge_out[(size_t)e * 64 + q * 4];
#pragma unroll
          for (int j = 0; j < 4; j++) vb[j] += u[j];
        }
      }
      u16x4 hb;
#pragma unroll
      for (int j = 0; j < 4; j++) hb[j] = f2h(vb[j]);
      *(u16x4*)&sm[r * N_XS + 4 * q] = ha;
      *(u16x4*)&sm[r * N_XS + 64 + 4 * q] = hb;
    }
    __syncthreads();

    // ---- layer 1 ----
    f4 a0 = {0.f, 0.f, 0.f, 0.f}, a1 = {0.f, 0.f, 0.f, 0.f};
#pragma unroll
    for (int s = 0; s < 4; s++) {
      const u16x8 av = *(const u16x8*)&sm[(wr1 * 16 + l15) * N_XS + s * 32 + g * 8];
      a0 = MF(av, b1f[s][0], a0);
      a1 = MF(av, b1f[s][1], a1);
    }
#pragma unroll
    for (int reg = 0; reg < 4; reg++) {
      const int row = wr1 * 16 + 4 * g + reg;
      sm[N_HO + row * N_XS + wc1 * 32 + l15] = f2h(fmaxf(a0[reg] + bias1_0, 0.f));
      sm[N_HO + row * N_XS + wc1 * 32 + 16 + l15] = f2h(fmaxf(a1[reg] + bias1_1, 0.f));
    }
    __syncthreads();

    // ---- layer 2 ----
    f4 a2 = {0.f, 0.f, 0.f, 0.f};
#pragma unroll
    for (int s = 0; s < 4; s++) {
      const u16x8 av =
          *(const u16x8*)&sm[N_HO + (wr2 * 16 + l15) * N_XS + s * 32 + g * 8];
      a2 = MF(av, b2f[s], a2);
    }
    {
      float* ob = (float*)&sm[N_OB];
#pragma unroll
      for (int reg = 0; reg < 4; reg++) {
        const int row = wr2 * 16 + 4 * g + reg;
        ob[row * 64 + wc2 * 16 + l15] = fmaxf(a2[reg] + bias2, 0.f);
      }
    }
    __syncthreads();

    // ---- LayerNorm + store ----
    if (t < 256) {
      const float* ob = (const float*)&sm[N_OB];
      const int row = t >> 3, p = t & 7;
      const f4 v0 = *(const f4*)&ob[row * 64 + p * 8];
      const f4 v1 = *(const f4*)&ob[row * 64 + p * 8 + 4];
      float s = 0.f, s2 = 0.f;
#pragma unroll
      for (int j = 0; j < 4; j++) {
        s += v0[j] + v1[j];
        s2 += v0[j] * v0[j] + v1[j] * v1[j];
      }
      s += __shfl_xor(s, 1);  s += __shfl_xor(s, 2);  s += __shfl_xor(s, 4);
      s2 += __shfl_xor(s2, 1); s2 += __shfl_xor(s2, 2); s2 += __shfl_xor(s2, 4);
      const float mu = s * (1.f / 64.f);
      const float var = s2 * (1.f / 64.f) - mu * mu;
      const float rstd = rsqrtf(var + 1e-5f);
      const long n = nbase + row;
      if (n < NN) {
        f4 o0, o1;
#pragma unroll
        for (int j = 0; j < 4; j++) {
          o0[j] = (v0[j] - mu) * rstd * ga0[j] + be0[j];
          o1[j] = (v1[j] - mu) * rstd * ga1[j] + be1[j];
        }
        float* op = node_out + (size_t)n * 64 + p * 8;
        *(f4*)op = o0;
        *(f4*)(op + 4) = o1;
      }
    }
  }
}

extern "C" void kernel_launch(void* const* d_in, const int* in_sizes, int n_in,
                              void* d_out, int out_size, void* d_ws, size_t ws_size,
                              hipStream_t stream) {
  const float* edge_attr = (const float*)d_in[0];
  const float* node_attr = (const float*)d_in[1];
  const int* eidx = (const int*)d_in[2];
  // d_in[3] = batch (unused)
  const float* eW1 = (const float*)d_in[4];
  const float* eb1 = (const float*)d_in[5];
  const float* eW2 = (const float*)d_in[6];
  const float* eb2 = (const float*)d_in[7];
  const float* eg = (const float*)d_in[8];
  const float* ebt = (const float*)d_in[9];
  const float* nW1 = (const float*)d_in[10];
  const float* nb1 = (const float*)d_in[11];
  const float* nW2 = (const float*)d_in[12];
  const float* nb2 = (const float*)d_in[13];
  const float* ng = (const float*)d_in[14];
  const float* nbt = (const float*)d_in[15];

  float* out_edge = (float*)d_out;
  float* out_node = out_edge + (size_t)NE * 64;

  // workspace: nh (f16 node_attr, 6.4 MB) then CSR ints
  u16* nh = (u16*)d_ws;
  int* deg = (int*)((char*)d_ws + (size_t)NN * 64 * 2);
  int* offsets = deg + NN;
  int* cur = offsets + NN + 1;
  int* elist = cur + NN;

  const int n4 = NN * 64 / 4;
  cvt_kernel<<<(n4 + 255) / 256, 256, 0, stream>>>(node_attr, nh, n4);
  zero_int_kernel<<<(NN + 255) / 256, 256, 0, stream>>>(deg, NN);
  hist_kernel<<<(NE + 255) / 256, 256, 0, stream>>>(eidx, deg);
  scan_kernel<<<1, 1024, 0, stream>>>(deg, offsets, cur);
  scatter_kernel<<<(NE + 255) / 256, 256, 0, stream>>>(eidx, cur, elist);

  const int etiles = NE / 32;         // 25000
  const int ntiles = (NN + 31) / 32;  // 1563
  edge_mlp_kernel<<<512, 512, 0, stream>>>(edge_attr, nh, eidx,
                                           eW1, eb1, eW2, eb2, eg, ebt,
                                           out_edge, etiles);
  node_mlp_kernel<<<1024, 512, 0, stream>>>(nh, out_edge, offsets, elist,
                                            nW1, nb1, nW2, nb2, ng, nbt,
                                            out_node, ntiles);
}

// Round 11
// 455.633 us; speedup vs baseline: 7.2295x; 1.6166x over previous
//
#include <hip/hip_runtime.h>

typedef float f4 __attribute__((ext_vector_type(4)));
typedef _Float16 f16;
typedef f16 f16x8 __attribute__((ext_vector_type(8)));
typedef unsigned short u16;
typedef u16 u16x4 __attribute__((ext_vector_type(4)));
typedef u16 u16x8 __attribute__((ext_vector_type(8)));

#define NE 800000
#define NN 50000

static __device__ __forceinline__ f4 MF(u16x8 a, u16x8 b, f4 c) {
  return __builtin_amdgcn_mfma_f32_16x16x32_f16(
      __builtin_bit_cast(f16x8, a), __builtin_bit_cast(f16x8, b), c, 0, 0, 0);
}
static __device__ __forceinline__ u16 f2h(float x) {
  return __builtin_bit_cast(u16, (f16)x);
}

// ---------------- prologue kernels ----------------
__global__ void cvt_kernel(const float* __restrict__ na, u16* __restrict__ nh,
                           int n4) {
  int i = blockIdx.x * blockDim.x + threadIdx.x;
  if (i < n4) {
    const f4 v = ((const f4*)na)[i];
    u16x4 h;
#pragma unroll
    for (int j = 0; j < 4; j++) h[j] = f2h(v[j]);
    ((u16x4*)nh)[i] = h;
  }
}

__global__ void zero_int_kernel(int* __restrict__ p, int n) {
  int i = blockIdx.x * blockDim.x + threadIdx.x;
  if (i < n) p[i] = 0;
}

__global__ void hist_kernel(const int* __restrict__ eidx, int* __restrict__ deg) {
  int e = blockIdx.x * blockDim.x + threadIdx.x;
  if (e < NE) atomicAdd(&deg[eidx[NE + e]], 1);
}

__global__ __launch_bounds__(1024)
void scan_kernel(const int* __restrict__ deg, int* __restrict__ offsets,
                 int* __restrict__ cur) {
  __shared__ int buf[2][1024];
  const int t = threadIdx.x;
  const int CH = (NN + 1023) / 1024;  // 49
  const int s = t * CH;
  const int e = (s + CH < NN) ? s + CH : NN;
  int sum = 0;
  for (int i = s; i < e; i++) sum += deg[i];
  buf[0][t] = sum;
  __syncthreads();
  int src = 0;
  for (int d = 1; d < 1024; d <<= 1) {
    int v = buf[src][t];
    if (t >= d) v += buf[src][t - d];
    buf[src ^ 1][t] = v;
    src ^= 1;
    __syncthreads();
  }
  int run = buf[src][t] - sum;  // exclusive prefix
  for (int i = s; i < e; i++) {
    offsets[i] = run;
    cur[i] = run;
    run += deg[i];
  }
  if (e == NN) offsets[NN] = run;
}

__global__ void scatter_kernel(const int* __restrict__ eidx, int* __restrict__ cur,
                               int* __restrict__ elist) {
  int e = blockIdx.x * blockDim.x + threadIdx.x;
  if (e < NE) {
    int slot = atomicAdd(&cur[eidx[NE + e]], 1);
    elist[slot] = e;
  }
}

// ---- edge kernel LDS (u16 units): 64-row tiles ----
// x: 64 x 192, stride 200 -> [0, 12800)
// h: 64 x 128, stride 136 -> [12800, 21504)
// ob: f32 64x64 @ u16 ofs 21504 (8192 u16) -> total 29696 u16 = 59392 B
#define E_XS 200
#define E_HS 136
#define E_HO 12800
#define E_OB 21504

__global__ __launch_bounds__(512, 4)
void edge_mlp_kernel(const float* __restrict__ edge_attr,
                     const u16* __restrict__ nh,
                     const int* __restrict__ eidx,
                     const float* __restrict__ W1, const float* __restrict__ b1,
                     const float* __restrict__ W2, const float* __restrict__ b2,
                     const float* __restrict__ gamma, const float* __restrict__ beta,
                     float* __restrict__ edge_out, int ntiles) {
  __shared__ __align__(16) u16 sm[29696];
  const int t = threadIdx.x;
  const int wid = t >> 6, lane = t & 63, g = lane >> 4, l15 = lane & 15;
  const int wr1 = wid >> 2, wc1 = wid & 3;  // L1: 32 rows x 32 cols per wave
  const int wr2 = wid & 1, wc2 = wid >> 1;  // L2: 32 rows x 16 cols per wave

  // ---- weight fragments in registers (f16), loaded once ----
  u16x8 b1f[6][2], b2f[4];
#pragma unroll
  for (int s = 0; s < 6; s++)
#pragma unroll
    for (int ci = 0; ci < 2; ci++) {
      const int col = wc1 * 32 + ci * 16 + l15;
      u16x8 th;
#pragma unroll
      for (int i = 0; i < 8; i++) th[i] = f2h(W1[(s * 32 + g * 8 + i) * 128 + col]);
      b1f[s][ci] = th;
    }
#pragma unroll
  for (int s = 0; s < 4; s++) {
    const int col = wc2 * 16 + l15;
    u16x8 th;
#pragma unroll
    for (int i = 0; i < 8; i++) th[i] = f2h(W2[(s * 32 + g * 8 + i) * 64 + col]);
    b2f[s] = th;
  }
  const float bias1_0 = b1[wc1 * 32 + l15];
  const float bias1_1 = b1[wc1 * 32 + 16 + l15];
  const float bias2 = b2[wc2 * 16 + l15];

  // gather geometry: row r = t>>3 (0..63), 16B chunk c8 = (t&7)*8 per section
  const int r = t >> 3;
  const int c8 = (t & 7) * 8;

  int idxr, idxs;
  u16x8 grecv, gsend;
  f4 ge0, ge1;

#define IDX(TB)                                                \
  {                                                            \
    const long e_ = (long)(TB)*64 + r;                         \
    idxr = eidx[NE + e_];                                      \
    idxs = eidx[e_];                                           \
  }
#define ROWS(TB)                                               \
  {                                                            \
    grecv = *(const u16x8*)&nh[(size_t)idxr * 64 + c8];        \
    gsend = *(const u16x8*)&nh[(size_t)idxs * 64 + c8];        \
    const float* ep_ =                                         \
        &edge_attr[((size_t)(TB)*64 + r) * 64 + c8];           \
    ge0 = *(const f4*)ep_;                                     \
    ge1 = *(const f4*)(ep_ + 4);                               \
  }

  const int G = gridDim.x;
  const int last = ntiles - 1;
  IDX(blockIdx.x);
  ROWS(blockIdx.x);
  {
    int tn = blockIdx.x + G;
    if (tn > last) tn = last;
    IDX(tn);
  }

  for (int tile = blockIdx.x; tile < ntiles; tile += G) {
    // ---- write prefetched x tile -> LDS ----
    *(u16x8*)&sm[r * E_XS + c8] = grecv;
    *(u16x8*)&sm[r * E_XS + 64 + c8] = gsend;
    {
      u16x8 he;
#pragma unroll
      for (int j = 0; j < 4; j++) {
        he[j] = f2h(ge0[j]);
        he[4 + j] = f2h(ge1[j]);
      }
      *(u16x8*)&sm[r * E_XS + 128 + c8] = he;
    }
    __syncthreads();  // B1: x visible

    // ---- issue next tile's rows (indices ready) + indices two ahead ----
    {
      int tn = tile + G;
      if (tn > last) tn = last;
      ROWS(tn);
      int tn2 = tile + 2 * G;
      if (tn2 > last) tn2 = last;
      IDX(tn2);
    }

    // ---- layer 1: per-wave 32x32 tile of h = relu(x @ W1 + b1) ----
    f4 acc00 = {0.f, 0.f, 0.f, 0.f}, acc01 = {0.f, 0.f, 0.f, 0.f};
    f4 acc10 = {0.f, 0.f, 0.f, 0.f}, acc11 = {0.f, 0.f, 0.f, 0.f};
#pragma unroll
    for (int s = 0; s < 6; s++) {
      const int k = s * 32 + g * 8;
      const u16x8 a0 = *(const u16x8*)&sm[(wr1 * 32 + l15) * E_XS + k];
      const u16x8 a1 = *(const u16x8*)&sm[(wr1 * 32 + 16 + l15) * E_XS + k];
      acc00 = MF(a0, b1f[s][0], acc00);
      acc01 = MF(a0, b1f[s][1], acc01);
      acc10 = MF(a1, b1f[s][0], acc10);
      acc11 = MF(a1, b1f[s][1], acc11);
    }
#pragma unroll
    for (int reg = 0; reg < 4; reg++) {
      const int row0 = wr1 * 32 + 4 * g + reg;
      const int row1 = row0 + 16;
      sm[E_HO + row0 * E_HS + wc1 * 32 + l15] = f2h(fmaxf(acc00[reg] + bias1_0, 0.f));
      sm[E_HO + row0 * E_HS + wc1 * 32 + 16 + l15] = f2h(fmaxf(acc01[reg] + bias1_1, 0.f));
      sm[E_HO + row1 * E_HS + wc1 * 32 + l15] = f2h(fmaxf(acc10[reg] + bias1_0, 0.f));
      sm[E_HO + row1 * E_HS + wc1 * 32 + 16 + l15] = f2h(fmaxf(acc11[reg] + bias1_1, 0.f));
    }
    __syncthreads();  // B2: h visible

    // ---- layer 2: per-wave 32x16 tile of o = relu(h @ W2 + b2) ----
    f4 a20 = {0.f, 0.f, 0.f, 0.f}, a21 = {0.f, 0.f, 0.f, 0.f};
#pragma unroll
    for (int s = 0; s < 4; s++) {
      const int k = s * 32 + g * 8;
      const u16x8 h0 = *(const u16x8*)&sm[E_HO + (wr2 * 32 + l15) * E_HS + k];
      const u16x8 h1 = *(const u16x8*)&sm[E_HO + (wr2 * 32 + 16 + l15) * E_HS + k];
      a20 = MF(h0, b2f[s], a20);
      a21 = MF(h1, b2f[s], a21);
    }
    {
      float* ob = (float*)&sm[E_OB];
#pragma unroll
      for (int reg = 0; reg < 4; reg++) {
        const int row0 = wr2 * 32 + 4 * g + reg;
        ob[row0 * 64 + wc2 * 16 + l15] = fmaxf(a20[reg] + bias2, 0.f);
        ob[(row0 + 16) * 64 + wc2 * 16 + l15] = fmaxf(a21[reg] + bias2, 0.f);
      }
    }
    __syncthreads();  // B3: ob visible (also fences x reads before next x write)

    // ---- LayerNorm + store (all 512 threads: 64 rows x 8 lanes) ----
    {
      const float* ob = (const float*)&sm[E_OB];
      const int p = t & 7;
      const f4 v0 = *(const f4*)&ob[r * 64 + p * 8];
      const f4 v1 = *(const f4*)&ob[r * 64 + p * 8 + 4];
      float s = 0.f, s2 = 0.f;
#pragma unroll
      for (int j = 0; j < 4; j++) {
        s += v0[j] + v1[j];
        s2 += v0[j] * v0[j] + v1[j] * v1[j];
      }
      s += __shfl_xor(s, 1);  s += __shfl_xor(s, 2);  s += __shfl_xor(s, 4);
      s2 += __shfl_xor(s2, 1); s2 += __shfl_xor(s2, 2); s2 += __shfl_xor(s2, 4);
      const float mu = s * (1.f / 64.f);
      const float var = s2 * (1.f / 64.f) - mu * mu;
      const float rstd = rsqrtf(var + 1e-5f);
      const f4 ga0 = *(const f4*)&gamma[p * 8];
      const f4 ga1 = *(const f4*)&gamma[p * 8 + 4];
      const f4 be0 = *(const f4*)&beta[p * 8];
      const f4 be1 = *(const f4*)&beta[p * 8 + 4];
      f4 o0, o1;
#pragma unroll
      for (int j = 0; j < 4; j++) {
        o0[j] = (v0[j] - mu) * rstd * ga0[j] + be0[j];
        o1[j] = (v1[j] - mu) * rstd * ga1[j] + be1[j];
      }
      float* op = edge_out + ((size_t)tile * 64 + r) * 64 + p * 8;
      *(f4*)op = o0;
      *(f4*)(op + 4) = o1;
    }
  }
#undef IDX
#undef ROWS
}

// ---- node kernel LDS (u16): x[0,4352) h[4352,8704) ob f32 @8704 ----
#define N_XS 136
#define N_HO 4352
#define N_OB 8704

__global__ __launch_bounds__(512, 2)
void node_mlp_kernel(const u16* __restrict__ nh,
                     const float* __restrict__ edge_out,
                     const int* __restrict__ offsets,
                     const int* __restrict__ elist,
                     const float* __restrict__ W1, const float* __restrict__ b1,
                     const float* __restrict__ W2, const float* __restrict__ b2,
                     const float* __restrict__ gamma, const float* __restrict__ beta,
                     float* __restrict__ node_out, int ntiles) {
  __shared__ __align__(16) u16 sm[12800];
  const int t = threadIdx.x;
  const int wid = t >> 6, lane = t & 63, g = lane >> 4, l15 = lane & 15;
  const int wr1 = wid >> 2, wc1 = wid & 3;
  const int wr2 = wid & 1, wc2 = wid >> 1;

  u16x8 b1f[4][2], b2f[4];
#pragma unroll
  for (int s = 0; s < 4; s++)
#pragma unroll
    for (int ci = 0; ci < 2; ci++) {
      const int col = wc1 * 32 + ci * 16 + l15;
      u16x8 th;
#pragma unroll
      for (int i = 0; i < 8; i++) th[i] = f2h(W1[(s * 32 + g * 8 + i) * 128 + col]);
      b1f[s][ci] = th;
    }
#pragma unroll
  for (int s = 0; s < 4; s++) {
    const int col = wc2 * 16 + l15;
    u16x8 th;
#pragma unroll
    for (int i = 0; i < 8; i++) th[i] = f2h(W2[(s * 32 + g * 8 + i) * 64 + col]);
    b2f[s] = th;
  }
  const float bias1_0 = b1[wc1 * 32 + l15];
  const float bias1_1 = b1[wc1 * 32 + 16 + l15];
  const float bias2 = b2[wc2 * 16 + l15];

  for (int tile = blockIdx.x; tile < ntiles; tile += gridDim.x) {
    const long nbase = (long)tile * 32;
    __syncthreads();  // protect x region across iterations

    // ---- gather x = [node_attr(f16) | csr-sum(edge_out)] ----
    {
      const int r = t >> 4, q = t & 15;
      const long n = nbase + r;
      u16x4 ha = {0, 0, 0, 0};
      f4 vb = {0.f, 0.f, 0.f, 0.f};
      if (n < NN) {
        ha = *(const u16x4*)&nh[(size_t)n * 64 + q * 4];
        const int o0 = offsets[n], o1 = offsets[n + 1];
        int i = o0;
        for (; i + 8 <= o1; i += 8) {
          int e[8];
#pragma unroll
          for (int j = 0; j < 8; j++) e[j] = elist[i + j];
          f4 u[8];
#pragma unroll
          for (int j = 0; j < 8; j++)
            u[j] = *(const f4*)&edge_out[(size_t)e[j] * 64 + q * 4];
#pragma unroll
          for (int j = 0; j < 8; j++)
#pragma unroll
            for (int k = 0; k < 4; k++) vb[k] += u[j][k];
        }
        for (; i < o1; i++) {
          const int e = elist[i];
          const f4 u = *(const f4*)&edge_out[(size_t)e * 64 + q * 4];
#pragma unroll
          for (int j = 0; j < 4; j++) vb[j] += u[j];
        }
      }
      u16x4 hb;
#pragma unroll
      for (int j = 0; j < 4; j++) hb[j] = f2h(vb[j]);
      *(u16x4*)&sm[r * N_XS + 4 * q] = ha;
      *(u16x4*)&sm[r * N_XS + 64 + 4 * q] = hb;
    }
    __syncthreads();

    // ---- layer 1 ----
    f4 a0 = {0.f, 0.f, 0.f, 0.f}, a1 = {0.f, 0.f, 0.f, 0.f};
#pragma unroll
    for (int s = 0; s < 4; s++) {
      const u16x8 av = *(const u16x8*)&sm[(wr1 * 16 + l15) * N_XS + s * 32 + g * 8];
      a0 = MF(av, b1f[s][0], a0);
      a1 = MF(av, b1f[s][1], a1);
    }
#pragma unroll
    for (int reg = 0; reg < 4; reg++) {
      const int row = wr1 * 16 + 4 * g + reg;
      sm[N_HO + row * N_XS + wc1 * 32 + l15] = f2h(fmaxf(a0[reg] + bias1_0, 0.f));
      sm[N_HO + row * N_XS + wc1 * 32 + 16 + l15] = f2h(fmaxf(a1[reg] + bias1_1, 0.f));
    }
    __syncthreads();

    // ---- layer 2 ----
    f4 a2 = {0.f, 0.f, 0.f, 0.f};
#pragma unroll
    for (int s = 0; s < 4; s++) {
      const u16x8 av =
          *(const u16x8*)&sm[N_HO + (wr2 * 16 + l15) * N_XS + s * 32 + g * 8];
      a2 = MF(av, b2f[s], a2);
    }
    {
      float* ob = (float*)&sm[N_OB];
#pragma unroll
      for (int reg = 0; reg < 4; reg++) {
        const int row = wr2 * 16 + 4 * g + reg;
        ob[row * 64 + wc2 * 16 + l15] = fmaxf(a2[reg] + bias2, 0.f);
      }
    }
    __syncthreads();

    // ---- LayerNorm + store ----
    if (t < 256) {
      const float* ob = (const float*)&sm[N_OB];
      const int row = t >> 3, p = t & 7;
      const f4 v0 = *(const f4*)&ob[row * 64 + p * 8];
      const f4 v1 = *(const f4*)&ob[row * 64 + p * 8 + 4];
      float s = 0.f, s2 = 0.f;
#pragma unroll
      for (int j = 0; j < 4; j++) {
        s += v0[j] + v1[j];
        s2 += v0[j] * v0[j] + v1[j] * v1[j];
      }
      s += __shfl_xor(s, 1);  s += __shfl_xor(s, 2);  s += __shfl_xor(s, 4);
      s2 += __shfl_xor(s2, 1); s2 += __shfl_xor(s2, 2); s2 += __shfl_xor(s2, 4);
      const float mu = s * (1.f / 64.f);
      const float var = s2 * (1.f / 64.f) - mu * mu;
      const float rstd = rsqrtf(var + 1e-5f);
      const long n = nbase + row;
      if (n < NN) {
        const f4 ga0 = *(const f4*)&gamma[p * 8];
        const f4 ga1 = *(const f4*)&gamma[p * 8 + 4];
        const f4 be0 = *(const f4*)&beta[p * 8];
        const f4 be1 = *(const f4*)&beta[p * 8 + 4];
        f4 o0, o1;
#pragma unroll
        for (int j = 0; j < 4; j++) {
          o0[j] = (v0[j] - mu) * rstd * ga0[j] + be0[j];
          o1[j] = (v1[j] - mu) * rstd * ga1[j] + be1[j];
        }
        float* op = node_out + (size_t)n * 64 + p * 8;
        *(f4*)op = o0;
        *(f4*)(op + 4) = o1;
      }
    }
  }
}

extern "C" void kernel_launch(void* const* d_in, const int* in_sizes, int n_in,
                              void* d_out, int out_size, void* d_ws, size_t ws_size,
                              hipStream_t stream) {
  const float* edge_attr = (const float*)d_in[0];
  const float* node_attr = (const float*)d_in[1];
  const int* eidx = (const int*)d_in[2];
  // d_in[3] = batch (unused)
  const float* eW1 = (const float*)d_in[4];
  const float* eb1 = (const float*)d_in[5];
  const float* eW2 = (const float*)d_in[6];
  const float* eb2 = (const float*)d_in[7];
  const float* eg = (const float*)d_in[8];
  const float* ebt = (const float*)d_in[9];
  const float* nW1 = (const float*)d_in[10];
  const float* nb1 = (const float*)d_in[11];
  const float* nW2 = (const float*)d_in[12];
  const float* nb2 = (const float*)d_in[13];
  const float* ng = (const float*)d_in[14];
  const float* nbt = (const float*)d_in[15];

  float* out_edge = (float*)d_out;
  float* out_node = out_edge + (size_t)NE * 64;

  // workspace: nh (f16 node_attr, 6.4 MB) then CSR ints
  u16* nh = (u16*)d_ws;
  int* deg = (int*)((char*)d_ws + (size_t)NN * 64 * 2);
  int* offsets = deg + NN;
  int* cur = offsets + NN + 1;
  int* elist = cur + NN;

  const int n4 = NN * 64 / 4;
  cvt_kernel<<<(n4 + 255) / 256, 256, 0, stream>>>(node_attr, nh, n4);
  zero_int_kernel<<<(NN + 255) / 256, 256, 0, stream>>>(deg, NN);
  hist_kernel<<<(NE + 255) / 256, 256, 0, stream>>>(eidx, deg);
  scan_kernel<<<1, 1024, 0, stream>>>(deg, offsets, cur);
  scatter_kernel<<<(NE + 255) / 256, 256, 0, stream>>>(eidx, cur, elist);

  const int etiles = NE / 64;         // 12500
  const int ntiles = (NN + 31) / 32;  // 1563
  edge_mlp_kernel<<<512, 512, 0, stream>>>(edge_attr, nh, eidx,
                                           eW1, eb1, eW2, eb2, eg, ebt,
                                           out_edge, etiles);
  node_mlp_kernel<<<1024, 512, 0, stream>>>(nh, out_edge, offsets, elist,
                                            nW1, nb1, nW2, nb2, ng, nbt,
                                            out_node, ntiles);
}

// Round 13
// 426.864 us; speedup vs baseline: 7.7167x; 1.0674x over previous
//
#include <hip/hip_runtime.h>

typedef float f4 __attribute__((ext_vector_type(4)));
typedef _Float16 f16;
typedef f16 f16x8 __attribute__((ext_vector_type(8)));
typedef unsigned short u16;
typedef u16 u16x4 __attribute__((ext_vector_type(4)));
typedef u16 u16x8 __attribute__((ext_vector_type(8)));

#define NE 800000
#define NN 50000

static __device__ __forceinline__ f4 MF(u16x8 a, u16x8 b, f4 c) {
  return __builtin_amdgcn_mfma_f32_16x16x32_f16(
      __builtin_bit_cast(f16x8, a), __builtin_bit_cast(f16x8, b), c, 0, 0, 0);
}
static __device__ __forceinline__ u16 f2h(float x) {
  return __builtin_bit_cast(u16, (f16)x);
}

// ---------------- prologue kernels (round-11 proven versions) ----------------
__global__ void cvt_kernel(const float* __restrict__ na, u16* __restrict__ nh,
                           int n4) {
  int i = blockIdx.x * blockDim.x + threadIdx.x;
  if (i < n4) {
    const f4 v = ((const f4*)na)[i];
    u16x4 h;
#pragma unroll
    for (int j = 0; j < 4; j++) h[j] = f2h(v[j]);
    ((u16x4*)nh)[i] = h;
  }
}

__global__ void zero_int_kernel(int* __restrict__ p, int n) {
  int i = blockIdx.x * blockDim.x + threadIdx.x;
  if (i < n) p[i] = 0;
}

__global__ void hist_kernel(const int* __restrict__ eidx, int* __restrict__ deg) {
  int e = blockIdx.x * blockDim.x + threadIdx.x;
  if (e < NE) atomicAdd(&deg[eidx[NE + e]], 1);
}

__global__ __launch_bounds__(1024)
void scan_kernel(const int* __restrict__ deg, int* __restrict__ offsets,
                 int* __restrict__ cur) {
  __shared__ int buf[2][1024];
  const int t = threadIdx.x;
  const int CH = (NN + 1023) / 1024;  // 49
  const int s = t * CH;
  const int e = (s + CH < NN) ? s + CH : NN;
  int sum = 0;
  for (int i = s; i < e; i++) sum += deg[i];
  buf[0][t] = sum;
  __syncthreads();
  int src = 0;
  for (int d = 1; d < 1024; d <<= 1) {
    int v = buf[src][t];
    if (t >= d) v += buf[src][t - d];
    buf[src ^ 1][t] = v;
    src ^= 1;
    __syncthreads();
  }
  int run = buf[src][t] - sum;  // exclusive prefix
  for (int i = s; i < e; i++) {
    offsets[i] = run;
    cur[i] = run;
    run += deg[i];
  }
  if (e == NN) offsets[NN] = run;
}

__global__ void scatter_kernel(const int* __restrict__ eidx, int* __restrict__ cur,
                               int* __restrict__ elist) {
  int e = blockIdx.x * blockDim.x + threadIdx.x;
  if (e < NE) {
    int slot = atomicAdd(&cur[eidx[NE + e]], 1);
    elist[slot] = e;
  }
}

// ---- edge kernel LDS (u16 units): 64-row tiles (round-11 proven) ----
#define E_XS 200
#define E_HS 136
#define E_HO 12800
#define E_OB 21504

__global__ __launch_bounds__(512, 4)
void edge_mlp_kernel(const float* __restrict__ edge_attr,
                     const u16* __restrict__ nh,
                     const int* __restrict__ eidx,
                     const float* __restrict__ W1, const float* __restrict__ b1,
                     const float* __restrict__ W2, const float* __restrict__ b2,
                     const float* __restrict__ gamma, const float* __restrict__ beta,
                     float* __restrict__ edge_out, int ntiles) {
  __shared__ __align__(16) u16 sm[29696];
  const int t = threadIdx.x;
  const int wid = t >> 6, lane = t & 63, g = lane >> 4, l15 = lane & 15;
  const int wr1 = wid >> 2, wc1 = wid & 3;  // L1: 32 rows x 32 cols per wave
  const int wr2 = wid & 1, wc2 = wid >> 1;  // L2: 32 rows x 16 cols per wave

  u16x8 b1f[6][2], b2f[4];
#pragma unroll
  for (int s = 0; s < 6; s++)
#pragma unroll
    for (int ci = 0; ci < 2; ci++) {
      const int col = wc1 * 32 + ci * 16 + l15;
      u16x8 th;
#pragma unroll
      for (int i = 0; i < 8; i++) th[i] = f2h(W1[(s * 32 + g * 8 + i) * 128 + col]);
      b1f[s][ci] = th;
    }
#pragma unroll
  for (int s = 0; s < 4; s++) {
    const int col = wc2 * 16 + l15;
    u16x8 th;
#pragma unroll
    for (int i = 0; i < 8; i++) th[i] = f2h(W2[(s * 32 + g * 8 + i) * 64 + col]);
    b2f[s] = th;
  }
  const float bias1_0 = b1[wc1 * 32 + l15];
  const float bias1_1 = b1[wc1 * 32 + 16 + l15];
  const float bias2 = b2[wc2 * 16 + l15];

  const int r = t >> 3;
  const int c8 = (t & 7) * 8;

  int idxr, idxs;
  u16x8 grecv, gsend;
  f4 ge0, ge1;

#define IDX(TB)                                                \
  {                                                            \
    const long e_ = (long)(TB)*64 + r;                         \
    idxr = eidx[NE + e_];                                      \
    idxs = eidx[e_];                                           \
  }
#define ROWS(TB)                                               \
  {                                                            \
    grecv = *(const u16x8*)&nh[(size_t)idxr * 64 + c8];        \
    gsend = *(const u16x8*)&nh[(size_t)idxs * 64 + c8];        \
    const float* ep_ =                                         \
        &edge_attr[((size_t)(TB)*64 + r) * 64 + c8];           \
    ge0 = __builtin_nontemporal_load((const f4*)ep_);          \
    ge1 = __builtin_nontemporal_load((const f4*)(ep_ + 4));    \
  }

  const int G = gridDim.x;
  const int last = ntiles - 1;
  IDX(blockIdx.x);
  ROWS(blockIdx.x);
  {
    int tn = blockIdx.x + G;
    if (tn > last) tn = last;
    IDX(tn);
  }

  for (int tile = blockIdx.x; tile < ntiles; tile += G) {
    // ---- write prefetched x tile -> LDS ----
    *(u16x8*)&sm[r * E_XS + c8] = grecv;
    *(u16x8*)&sm[r * E_XS + 64 + c8] = gsend;
    {
      u16x8 he;
#pragma unroll
      for (int j = 0; j < 4; j++) {
        he[j] = f2h(ge0[j]);
        he[4 + j] = f2h(ge1[j]);
      }
      *(u16x8*)&sm[r * E_XS + 128 + c8] = he;
    }
    __syncthreads();  // B1: x visible

    // ---- issue next tile's rows (indices ready) + indices two ahead ----
    {
      int tn = tile + G;
      if (tn > last) tn = last;
      ROWS(tn);
      int tn2 = tile + 2 * G;
      if (tn2 > last) tn2 = last;
      IDX(tn2);
    }

    // ---- layer 1: per-wave 32x32 tile of h = relu(x @ W1 + b1) ----
    f4 acc00 = {0.f, 0.f, 0.f, 0.f}, acc01 = {0.f, 0.f, 0.f, 0.f};
    f4 acc10 = {0.f, 0.f, 0.f, 0.f}, acc11 = {0.f, 0.f, 0.f, 0.f};
#pragma unroll
    for (int s = 0; s < 6; s++) {
      const int k = s * 32 + g * 8;
      const u16x8 a0 = *(const u16x8*)&sm[(wr1 * 32 + l15) * E_XS + k];
      const u16x8 a1 = *(const u16x8*)&sm[(wr1 * 32 + 16 + l15) * E_XS + k];
      acc00 = MF(a0, b1f[s][0], acc00);
      acc01 = MF(a0, b1f[s][1], acc01);
      acc10 = MF(a1, b1f[s][0], acc10);
      acc11 = MF(a1, b1f[s][1], acc11);
    }
#pragma unroll
    for (int reg = 0; reg < 4; reg++) {
      const int row0 = wr1 * 32 + 4 * g + reg;
      const int row1 = row0 + 16;
      sm[E_HO + row0 * E_HS + wc1 * 32 + l15] = f2h(fmaxf(acc00[reg] + bias1_0, 0.f));
      sm[E_HO + row0 * E_HS + wc1 * 32 + 16 + l15] = f2h(fmaxf(acc01[reg] + bias1_1, 0.f));
      sm[E_HO + row1 * E_HS + wc1 * 32 + l15] = f2h(fmaxf(acc10[reg] + bias1_0, 0.f));
      sm[E_HO + row1 * E_HS + wc1 * 32 + 16 + l15] = f2h(fmaxf(acc11[reg] + bias1_1, 0.f));
    }
    __syncthreads();  // B2: h visible

    // ---- layer 2: per-wave 32x16 tile of o = relu(h @ W2 + b2) ----
    f4 a20 = {0.f, 0.f, 0.f, 0.f}, a21 = {0.f, 0.f, 0.f, 0.f};
#pragma unroll
    for (int s = 0; s < 4; s++) {
      const int k = s * 32 + g * 8;
      const u16x8 h0 = *(const u16x8*)&sm[E_HO + (wr2 * 32 + l15) * E_HS + k];
      const u16x8 h1 = *(const u16x8*)&sm[E_HO + (wr2 * 32 + 16 + l15) * E_HS + k];
      a20 = MF(h0, b2f[s], a20);
      a21 = MF(h1, b2f[s], a21);
    }
    {
      float* ob = (float*)&sm[E_OB];
#pragma unroll
      for (int reg = 0; reg < 4; reg++) {
        const int row0 = wr2 * 32 + 4 * g + reg;
        ob[row0 * 64 + wc2 * 16 + l15] = fmaxf(a20[reg] + bias2, 0.f);
        ob[(row0 + 16) * 64 + wc2 * 16 + l15] = fmaxf(a21[reg] + bias2, 0.f);
      }
    }
    __syncthreads();  // B3: ob visible (also fences x reads before next x write)

    // ---- LayerNorm + store (all 512 threads: 64 rows x 8 lanes) ----
    {
      const float* ob = (const float*)&sm[E_OB];
      const int p = t & 7;
      const f4 v0 = *(const f4*)&ob[r * 64 + p * 8];
      const f4 v1 = *(const f4*)&ob[r * 64 + p * 8 + 4];
      float s = 0.f, s2 = 0.f;
#pragma unroll
      for (int j = 0; j < 4; j++) {
        s += v0[j] + v1[j];
        s2 += v0[j] * v0[j] + v1[j] * v1[j];
      }
      s += __shfl_xor(s, 1);  s += __shfl_xor(s, 2);  s += __shfl_xor(s, 4);
      s2 += __shfl_xor(s2, 1); s2 += __shfl_xor(s2, 2); s2 += __shfl_xor(s2, 4);
      const float mu = s * (1.f / 64.f);
      const float var = s2 * (1.f / 64.f) - mu * mu;
      const float rstd = rsqrtf(var + 1e-5f);
      const f4 ga0 = *(const f4*)&gamma[p * 8];
      const f4 ga1 = *(const f4*)&gamma[p * 8 + 4];
      const f4 be0 = *(const f4*)&beta[p * 8];
      const f4 be1 = *(const f4*)&beta[p * 8 + 4];
      f4 o0, o1;
#pragma unroll
      for (int j = 0; j < 4; j++) {
        o0[j] = (v0[j] - mu) * rstd * ga0[j] + be0[j];
        o1[j] = (v1[j] - mu) * rstd * ga1[j] + be1[j];
      }
      float* op = edge_out + ((size_t)tile * 64 + r) * 64 + p * 8;
      __builtin_nontemporal_store(o0, (f4*)op);
      __builtin_nontemporal_store(o1, (f4*)(op + 4));
    }
  }
#undef IDX
#undef ROWS
}

// ---- node kernel LDS (u16): 64-row tiles, edge-kernel skeleton ----
// x: 64x128 stride 136 -> [0,8704); h: [8704,17408); ob f32 @17408 (8192 u16)
#define N_XS 136
#define N_HO 8704
#define N_OB 17408

__global__ __launch_bounds__(512, 4)
void node_mlp_kernel(const u16* __restrict__ nh,
                     const float* __restrict__ edge_out,
                     const int* __restrict__ offsets,
                     const int* __restrict__ elist,
                     const float* __restrict__ W1, const float* __restrict__ b1,
                     const float* __restrict__ W2, const float* __restrict__ b2,
                     const float* __restrict__ gamma, const float* __restrict__ beta,
                     float* __restrict__ node_out, int ntiles) {
  __shared__ __align__(16) u16 sm[25600];
  const int t = threadIdx.x;
  const int wid = t >> 6, lane = t & 63, g = lane >> 4, l15 = lane & 15;
  const int wr1 = wid >> 2, wc1 = wid & 3;
  const int wr2 = wid & 1, wc2 = wid >> 1;

  u16x8 b1f[4][2], b2f[4];
#pragma unroll
  for (int s = 0; s < 4; s++)
#pragma unroll
    for (int ci = 0; ci < 2; ci++) {
      const int col = wc1 * 32 + ci * 16 + l15;
      u16x8 th;
#pragma unroll
      for (int i = 0; i < 8; i++) th[i] = f2h(W1[(s * 32 + g * 8 + i) * 128 + col]);
      b1f[s][ci] = th;
    }
#pragma unroll
  for (int s = 0; s < 4; s++) {
    const int col = wc2 * 16 + l15;
    u16x8 th;
#pragma unroll
    for (int i = 0; i < 8; i++) th[i] = f2h(W2[(s * 32 + g * 8 + i) * 64 + col]);
    b2f[s] = th;
  }
  const float bias1_0 = b1[wc1 * 32 + l15];
  const float bias1_1 = b1[wc1 * 32 + 16 + l15];
  const float bias2 = b2[wc2 * 16 + l15];

  const int r = t >> 3, q = t & 7;

  for (int tile = blockIdx.x; tile < ntiles; tile += gridDim.x) {
    const long nbase = (long)tile * 64;
    __syncthreads();  // protect LDS across iterations

    // ---- gather x = [node_attr(f16) | csr-sum(edge_out)] ----
    {
      const long n = nbase + r;
      u16x8 ha = {0, 0, 0, 0, 0, 0, 0, 0};
      float ac[8];
#pragma unroll
      for (int j = 0; j < 8; j++) ac[j] = 0.f;
      if (n < NN) {
        ha = *(const u16x8*)&nh[(size_t)n * 64 + q * 8];
        const int o0 = offsets[n], o1 = offsets[n + 1];
        int i = o0;
        for (; i + 4 <= o1; i += 4) {
          int e[4];
#pragma unroll
          for (int j = 0; j < 4; j++) e[j] = elist[i + j];
          f4 u0[4], u1[4];
#pragma unroll
          for (int j = 0; j < 4; j++) {
            u0[j] = *(const f4*)&edge_out[(size_t)e[j] * 64 + q * 8];
            u1[j] = *(const f4*)&edge_out[(size_t)e[j] * 64 + q * 8 + 4];
          }
#pragma unroll
          for (int j = 0; j < 4; j++)
#pragma unroll
            for (int k = 0; k < 4; k++) {
              ac[k] += u0[j][k];
              ac[k + 4] += u1[j][k];
            }
        }
        for (; i < o1; i++) {
          const int e = elist[i];
          const f4 u0 = *(const f4*)&edge_out[(size_t)e * 64 + q * 8];
          const f4 u1 = *(const f4*)&edge_out[(size_t)e * 64 + q * 8 + 4];
#pragma unroll
          for (int j = 0; j < 4; j++) {
            ac[j] += u0[j];
            ac[j + 4] += u1[j];
          }
        }
      }
      u16x8 hb;
#pragma unroll
      for (int j = 0; j < 8; j++) hb[j] = f2h(ac[j]);
      *(u16x8*)&sm[r * N_XS + q * 8] = ha;
      *(u16x8*)&sm[r * N_XS + 64 + q * 8] = hb;
    }
    __syncthreads();

    // ---- layer 1 ----
    f4 acc00 = {0.f, 0.f, 0.f, 0.f}, acc01 = {0.f, 0.f, 0.f, 0.f};
    f4 acc10 = {0.f, 0.f, 0.f, 0.f}, acc11 = {0.f, 0.f, 0.f, 0.f};
#pragma unroll
    for (int s = 0; s < 4; s++) {
      const int k = s * 32 + g * 8;
      const u16x8 a0 = *(const u16x8*)&sm[(wr1 * 32 + l15) * N_XS + k];
      const u16x8 a1 = *(const u16x8*)&sm[(wr1 * 32 + 16 + l15) * N_XS + k];
      acc00 = MF(a0, b1f[s][0], acc00);
      acc01 = MF(a0, b1f[s][1], acc01);
      acc10 = MF(a1, b1f[s][0], acc10);
      acc11 = MF(a1, b1f[s][1], acc11);
    }
#pragma unroll
    for (int reg = 0; reg < 4; reg++) {
      const int row0 = wr1 * 32 + 4 * g + reg;
      const int row1 = row0 + 16;
      sm[N_HO + row0 * N_XS + wc1 * 32 + l15] = f2h(fmaxf(acc00[reg] + bias1_0, 0.f));
      sm[N_HO + row0 * N_XS + wc1 * 32 + 16 + l15] = f2h(fmaxf(acc01[reg] + bias1_1, 0.f));
      sm[N_HO + row1 * N_XS + wc1 * 32 + l15] = f2h(fmaxf(acc10[reg] + bias1_0, 0.f));
      sm[N_HO + row1 * N_XS + wc1 * 32 + 16 + l15] = f2h(fmaxf(acc11[reg] + bias1_1, 0.f));
    }
    __syncthreads();

    // ---- layer 2 ----
    f4 a20 = {0.f, 0.f, 0.f, 0.f}, a21 = {0.f, 0.f, 0.f, 0.f};
#pragma unroll
    for (int s = 0; s < 4; s++) {
      const int k = s * 32 + g * 8;
      const u16x8 h0 = *(const u16x8*)&sm[N_HO + (wr2 * 32 + l15) * N_XS + k];
      const u16x8 h1 = *(const u16x8*)&sm[N_HO + (wr2 * 32 + 16 + l15) * N_XS + k];
      a20 = MF(h0, b2f[s], a20);
      a21 = MF(h1, b2f[s], a21);
    }
    {
      float* ob = (float*)&sm[N_OB];
#pragma unroll
      for (int reg = 0; reg < 4; reg++) {
        const int row0 = wr2 * 32 + 4 * g + reg;
        ob[row0 * 64 + wc2 * 16 + l15] = fmaxf(a20[reg] + bias2, 0.f);
        ob[(row0 + 16) * 64 + wc2 * 16 + l15] = fmaxf(a21[reg] + bias2, 0.f);
      }
    }
    __syncthreads();

    // ---- LayerNorm + store ----
    {
      const float* ob = (const float*)&sm[N_OB];
      const int p = t & 7;
      const f4 v0 = *(const f4*)&ob[r * 64 + p * 8];
      const f4 v1 = *(const f4*)&ob[r * 64 + p * 8 + 4];
      float s = 0.f, s2 = 0.f;
#pragma unroll
      for (int j = 0; j < 4; j++) {
        s += v0[j] + v1[j];
        s2 += v0[j] * v0[j] + v1[j] * v1[j];
      }
      s += __shfl_xor(s, 1);  s += __shfl_xor(s, 2);  s += __shfl_xor(s, 4);
      s2 += __shfl_xor(s2, 1); s2 += __shfl_xor(s2, 2); s2 += __shfl_xor(s2, 4);
      const float mu = s * (1.f / 64.f);
      const float var = s2 * (1.f / 64.f) - mu * mu;
      const float rstd = rsqrtf(var + 1e-5f);
      const long n = nbase + r;
      if (n < NN) {
        const f4 ga0 = *(const f4*)&gamma[p * 8];
        const f4 ga1 = *(const f4*)&gamma[p * 8 + 4];
        const f4 be0 = *(const f4*)&beta[p * 8];
        const f4 be1 = *(const f4*)&beta[p * 8 + 4];
        f4 o0, o1;
#pragma unroll
        for (int j = 0; j < 4; j++) {
          o0[j] = (v0[j] - mu) * rstd * ga0[j] + be0[j];
          o1[j] = (v1[j] - mu) * rstd * ga1[j] + be1[j];
        }
        float* op = node_out + (size_t)n * 64 + p * 8;
        __builtin_nontemporal_store(o0, (f4*)op);
        __builtin_nontemporal_store(o1, (f4*)(op + 4));
      }
    }
  }
}

extern "C" void kernel_launch(void* const* d_in, const int* in_sizes, int n_in,
                              void* d_out, int out_size, void* d_ws, size_t ws_size,
                              hipStream_t stream) {
  const float* edge_attr = (const float*)d_in[0];
  const float* node_attr = (const float*)d_in[1];
  const int* eidx = (const int*)d_in[2];
  // d_in[3] = batch (unused)
  const float* eW1 = (const float*)d_in[4];
  const float* eb1 = (const float*)d_in[5];
  const float* eW2 = (const float*)d_in[6];
  const float* eb2 = (const float*)d_in[7];
  const float* eg = (const float*)d_in[8];
  const float* ebt = (const float*)d_in[9];
  const float* nW1 = (const float*)d_in[10];
  const float* nb1 = (const float*)d_in[11];
  const float* nW2 = (const float*)d_in[12];
  const float* nb2 = (const float*)d_in[13];
  const float* ng = (const float*)d_in[14];
  const float* nbt = (const float*)d_in[15];

  float* out_edge = (float*)d_out;
  float* out_node = out_edge + (size_t)NE * 64;

  // workspace: nh (f16 node_attr, 6.4 MB) then CSR ints (round-11 layout)
  u16* nh = (u16*)d_ws;
  int* deg = (int*)((char*)d_ws + (size_t)NN * 64 * 2);
  int* offsets = deg + NN;
  int* cur = offsets + NN + 1;
  int* elist = cur + NN;

  const int n4 = NN * 64 / 4;
  cvt_kernel<<<(n4 + 255) / 256, 256, 0, stream>>>(node_attr, nh, n4);
  zero_int_kernel<<<(NN + 255) / 256, 256, 0, stream>>>(deg, NN);
  hist_kernel<<<(NE + 255) / 256, 256, 0, stream>>>(eidx, deg);
  scan_kernel<<<1, 1024, 0, stream>>>(deg, offsets, cur);
  scatter_kernel<<<(NE + 255) / 256, 256, 0, stream>>>(eidx, cur, elist);

  const int etiles = NE / 64;         // 12500
  const int ntiles = (NN + 63) / 64;  // 782
  edge_mlp_kernel<<<512, 512, 0, stream>>>(edge_attr, nh, eidx,
                                           eW1, eb1, eW2, eb2, eg, ebt,
                                           out_edge, etiles);
  node_mlp_kernel<<<ntiles, 512, 0, stream>>>(nh, out_edge, offsets, elist,
                                              nW1, nb1, nW2, nb2, ng, nbt,
                                              out_node, ntiles);
}